// Round 2
// baseline (14567.859 us; speedup 1.0000x reference)
//
#include <hip/hip_runtime.h>
#include <math.h>

#define NR 8192      // NA == NT
#define DIM 256
#define NBLK 512     // fused-kernel blocks == column-partial chunks (2 per CU)
#define CROWS 16     // rows per chunk
#define NSUB 8       // sub-chunks per chunk (2 rows each, reg ping-pong)
// 10 * log2(e): converts distances directly into base-2 log domain
#define SCALE2 14.426950408889634f

typedef unsigned short ushort_t;
typedef __attribute__((ext_vector_type(8))) short bfrag;   // 8 bf16 (4 VGPRs)
typedef __attribute__((ext_vector_type(4))) float facc;    // 4 fp32 acc

// v_exp_f32 / v_log_f32 are base-2 natively — use them raw
__device__ __forceinline__ float fexp2(float x) {
#if __has_builtin(__builtin_amdgcn_exp2f)
    return __builtin_amdgcn_exp2f(x);
#else
    return exp2f(x);
#endif
}
__device__ __forceinline__ float flog2(float x) {
#if __has_builtin(__builtin_amdgcn_logf)
    return __builtin_amdgcn_logf(x);
#else
    return log2f(x);
#endif
}

// base-2 online LSE combine
__device__ __forceinline__ void lse_comb2(float& m, float& s, float mo, float so) {
    float nm = fmaxf(m, mo);
    s = s * fexp2(m - nm) + so * fexp2(mo - nm);
    m = nm;
}

// grouped-4 online LSE update (1 tree-max + 1 correction exp per 4 values)
__device__ __forceinline__ void lse_upd4(float& m, float& s,
                                         float v0, float v1, float v2, float v3) {
    float m4 = fmaxf(fmaxf(v0, v1), fmaxf(v2, v3));
    float nm = fmaxf(m, m4);
    float e = fexp2(v0 - nm) + fexp2(v1 - nm) + fexp2(v2 - nm) + fexp2(v3 - nm);
    s = fmaf(s, fexp2(m - nm), e);
    m = nm;
}

// grouped-2 online LSE update
__device__ __forceinline__ void lse_upd2(float& m, float& s, float v0, float v1) {
    float m2 = fmaxf(v0, v1);
    float nm = fmaxf(m, m2);
    float e = fexp2(v0 - nm) + fexp2(v1 - nm);
    s = fmaf(s, fexp2(m - nm), e);
    m = nm;
}

// RNE float -> bf16 bits (manual: deterministic, no API variance)
__device__ __forceinline__ ushort_t f2bf(float x) {
    unsigned u = __float_as_uint(x);
    u += 0x7FFFu + ((u >> 16) & 1u);
    return (ushort_t)(u >> 16);
}
__device__ __forceinline__ float bf2f(ushort_t b) {
    return __uint_as_float(((unsigned)b) << 16);
}

// ---------------- init ----------------
__global__ void init_zero(float* __restrict__ g) {
    int t = blockIdx.x * 256 + threadIdx.x;
    if (t < NR) g[t] = 0.0f;
}

// ---------------- out[M,DIM] = A[M,DIM] @ W[DIM,DIM] + bias ----------------
__global__ __launch_bounds__(256) void gemm_qk(const float* __restrict__ A,
                                               const float* __restrict__ W,
                                               const float* __restrict__ bias,
                                               float* __restrict__ out) {
    __shared__ float As[16][68];
    __shared__ float Ws[16][68];
    const int t  = threadIdx.x;
    const int r0 = blockIdx.x * 64;
    const int c0 = blockIdx.y * 64;
    const int ty = t >> 4, tx = t & 15;
    const int arow = t >> 2;
    const int ak   = (t & 3) * 4;
    const int wrow = t >> 4;
    const int wcol = (t & 15) * 4;
    float acc[4][4] = {};
    for (int k0 = 0; k0 < DIM; k0 += 16) {
        float4 av = *(const float4*)(A + (size_t)(r0 + arow) * DIM + k0 + ak);
        float4 wv = *(const float4*)(W + (size_t)(k0 + wrow) * DIM + c0 + wcol);
        __syncthreads();
        As[ak + 0][arow] = av.x; As[ak + 1][arow] = av.y;
        As[ak + 2][arow] = av.z; As[ak + 3][arow] = av.w;
        *(float4*)&Ws[wrow][wcol] = wv;
        __syncthreads();
#pragma unroll
        for (int kk = 0; kk < 16; ++kk) {
            float4 a = *(const float4*)&As[kk][ty * 4];
            float4 b = *(const float4*)&Ws[kk][tx * 4];
            float aa[4] = {a.x, a.y, a.z, a.w};
            float bb[4] = {b.x, b.y, b.z, b.w};
#pragma unroll
            for (int i = 0; i < 4; ++i)
#pragma unroll
                for (int j = 0; j < 4; ++j)
                    acc[i][j] = fmaf(aa[i], bb[j], acc[i][j]);
        }
    }
#pragma unroll
    for (int i = 0; i < 4; ++i) {
        float4 o;
        o.x = acc[i][0] + bias[c0 + tx * 4 + 0];
        o.y = acc[i][1] + bias[c0 + tx * 4 + 1];
        o.z = acc[i][2] + bias[c0 + tx * 4 + 2];
        o.w = acc[i][3] + bias[c0 + tx * 4 + 3];
        *(float4*)(out + (size_t)(r0 + ty * 4 + i) * DIM + c0 + tx * 4) = o;
    }
}

// ---------------- row squared norms ----------------
__global__ __launch_bounds__(64) void row_norm(const float* __restrict__ x,
                                               float* __restrict__ out) {
    const int row = blockIdx.x, lane = threadIdx.x;
    float4 v = *(const float4*)(x + (size_t)row * DIM + lane * 4);
    float s = v.x * v.x + v.y * v.y + v.z * v.z + v.w * v.w;
#pragma unroll
    for (int off = 32; off > 0; off >>= 1) s += __shfl_xor(s, off);
    if (lane == 0) out[row] = s;
}

// ---------------- split fp32 -> bf16 hi + bf16 lo (lo = bf16(x - hi)) ----------------
__global__ __launch_bounds__(256) void split_bf16(const float* __restrict__ x,
                                                  ushort_t* __restrict__ hi,
                                                  ushort_t* __restrict__ lo) {
    const int idx = (blockIdx.x * 256 + threadIdx.x) * 4;
    float4 v = *(const float4*)(x + idx);
    ushort_t h0 = f2bf(v.x), h1 = f2bf(v.y), h2 = f2bf(v.z), h3 = f2bf(v.w);
    ushort4 hv = make_ushort4(h0, h1, h2, h3);
    ushort4 lv = make_ushort4(f2bf(v.x - bf2f(h0)), f2bf(v.y - bf2f(h1)),
                              f2bf(v.z - bf2f(h2)), f2bf(v.w - bf2f(h3)));
    *(ushort4*)(hi + idx) = hv;
    *(ushort4*)(lo + idx) = lv;
}

// ---------------- S = SCALE2*(qn_i + kn_j - 2*q_i.k_j) via split-bf16 MFMA ----------
// 4096 blocks x 256 threads (4 waves, 2x2 of 64x64). mfma_f32_16x16x32_bf16:
// A[m=lane&15][k=quad*8+j], B[n=lane&15][k=quad*8+j] -> contiguous 16 B/lane loads
// straight from global (row-major bf16, L2/L3-served). Full 4-product split
// (hh+hl+lh+ll): per-element error <= 2^-19 — adds ~4e-4 exponent error,
// negligible vs the ~1e-2 LSE accumulation error. C/D: col=lane&15,
// row=quad*4+reg (m89-verified).
__global__ __launch_bounds__(256) void dist_mfma(const ushort_t* __restrict__ qh,
                                                 const ushort_t* __restrict__ ql,
                                                 const ushort_t* __restrict__ kh,
                                                 const ushort_t* __restrict__ kl,
                                                 const float* __restrict__ qn,
                                                 const float* __restrict__ kn,
                                                 float* __restrict__ S) {
    const int t = threadIdx.x;
    const int wv = t >> 6, lane = t & 63;
    const int r0 = blockIdx.y * 128 + (wv >> 1) * 64;
    const int c0 = blockIdx.x * 128 + (wv & 1) * 64;
    const int fr = lane & 15;       // row (A) / col (B) within 16x16 tile
    const int fq = lane >> 4;       // quad -> k-subrange / C-row group
    facc acc[4][4];
#pragma unroll
    for (int i = 0; i < 4; ++i)
#pragma unroll
        for (int j = 0; j < 4; ++j) acc[i][j] = (facc){0.f, 0.f, 0.f, 0.f};

    for (int k0 = 0; k0 < DIM; k0 += 32) {
        const int ks = k0 + fq * 8;
        bfrag ah[4], al[4], bh[4], bl[4];
#pragma unroll
        for (int mi = 0; mi < 4; ++mi) {
            const size_t ao = (size_t)(r0 + mi * 16 + fr) * DIM + ks;
            ah[mi] = *(const bfrag*)(qh + ao);
            al[mi] = *(const bfrag*)(ql + ao);
        }
#pragma unroll
        for (int ni = 0; ni < 4; ++ni) {
            const size_t bo = (size_t)(c0 + ni * 16 + fr) * DIM + ks;
            bh[ni] = *(const bfrag*)(kh + bo);
            bl[ni] = *(const bfrag*)(kl + bo);
        }
#pragma unroll
        for (int mi = 0; mi < 4; ++mi)
#pragma unroll
            for (int ni = 0; ni < 4; ++ni) {
                acc[mi][ni] = __builtin_amdgcn_mfma_f32_16x16x32_bf16(ah[mi], bh[ni], acc[mi][ni], 0, 0, 0);
                acc[mi][ni] = __builtin_amdgcn_mfma_f32_16x16x32_bf16(ah[mi], bl[ni], acc[mi][ni], 0, 0, 0);
                acc[mi][ni] = __builtin_amdgcn_mfma_f32_16x16x32_bf16(al[mi], bh[ni], acc[mi][ni], 0, 0, 0);
                acc[mi][ni] = __builtin_amdgcn_mfma_f32_16x16x32_bf16(al[mi], bl[ni], acc[mi][ni], 0, 0, 0);
            }
    }
    // epilogue: S[row][col] = (qn + kn - 2*dot) * SCALE2
#pragma unroll
    for (int mi = 0; mi < 4; ++mi) {
        float qnr[4];
#pragma unroll
        for (int r = 0; r < 4; ++r) qnr[r] = qn[r0 + mi * 16 + fq * 4 + r];
#pragma unroll
        for (int ni = 0; ni < 4; ++ni) {
            const int col = c0 + ni * 16 + fr;
            const float knc = kn[col];
#pragma unroll
            for (int r = 0; r < 4; ++r) {
                const int row = r0 + mi * 16 + fq * 4 + r;
                S[(size_t)row * NR + col] = (qnr[r] + knc - 2.0f * acc[mi][ni][r]) * SCALE2;
            }
        }
    }
}

// ---------------- MLP logits: relu(A@W1+b1)@W2 + b2 ----------------
__global__ __launch_bounds__(128) void mlp_logits(const float* __restrict__ A,
                                                  const float* __restrict__ W1,
                                                  const float* __restrict__ b1,
                                                  const float* __restrict__ W2,
                                                  const float* __restrict__ b2,
                                                  float* __restrict__ logits) {
    __shared__ float ar[DIM];
    __shared__ float red[2];
    const int t = threadIdx.x;
    const int row = blockIdx.x;
    *(float2*)&ar[t * 2] = *(const float2*)(A + (size_t)row * DIM + t * 2);
    __syncthreads();
    float h = b1[t];
#pragma unroll 8
    for (int kk = 0; kk < DIM; ++kk) h = fmaf(ar[kk], W1[kk * 128 + t], h);
    float val = fmaxf(h, 0.0f) * W2[t];
#pragma unroll
    for (int off = 32; off > 0; off >>= 1) val += __shfl_xor(val, off);
    if ((t & 63) == 0) red[t >> 6] = val;
    __syncthreads();
    if (t == 0) logits[row] = red[0] + red[1] + b2[0];
}

// ---------------- softmax over 8192 logits -> log2(b + 1e-20) ----------------
__global__ __launch_bounds__(1024) void softmax_logb(const float* __restrict__ logits,
                                                     float* __restrict__ logb2) {
    __shared__ float redm[16], reds[16];
    const int t = threadIdx.x;
    float l[8];
    float m = -INFINITY;
#pragma unroll
    for (int i = 0; i < 8; ++i) { l[i] = logits[i * 1024 + t]; m = fmaxf(m, l[i]); }
#pragma unroll
    for (int off = 32; off > 0; off >>= 1) m = fmaxf(m, __shfl_xor(m, off));
    if ((t & 63) == 0) redm[t >> 6] = m;
    __syncthreads();
    if (t < 64) {
        float v = (t < 16) ? redm[t] : -INFINITY;
#pragma unroll
        for (int off = 8; off > 0; off >>= 1) v = fmaxf(v, __shfl_xor(v, off));
        if (t == 0) redm[0] = v;
    }
    __syncthreads();
    m = redm[0];
    float s = 0.0f;
#pragma unroll
    for (int i = 0; i < 8; ++i) s += __expf(l[i] - m);
#pragma unroll
    for (int off = 32; off > 0; off >>= 1) s += __shfl_xor(s, off);
    if ((t & 63) == 0) reds[t >> 6] = s;
    __syncthreads();
    if (t < 64) {
        float v = (t < 16) ? reds[t] : 0.0f;
#pragma unroll
        for (int off = 8; off > 0; off >>= 1) v += __shfl_xor(v, off);
        if (t == 0) reds[0] = v;
    }
    __syncthreads();
    s = reds[0];
    float invs = 1.0f / s;
#pragma unroll
    for (int i = 0; i < 8; ++i)
        logb2[i * 1024 + t] = log2f(__expf(l[i] - m) * invs + 1e-20f);
}

// ---------------- fused iteration: wave-aligned, REGISTER-direct, LDS-free S -------
// Each wave owns a 1024-col segment for ALL 16 rows of its chunk. Thread t owns
// cols {wv*1024 + lane*4 + it*256 + c}. Sub-chunk = 2 rows loaded straight into
// registers (8x global_load_dwordx4), ping-pong bva/bvb issued one sub-chunk
// ahead — compiler's scoreboard emits counted vmcnt waits; loads stay in flight
// across the raw (non-draining) barrier. Phase 1 and phase 2 consume the SAME
// 32 register floats, so S never touches LDS and barrier B disappears: ONE
// barrier per sub-chunk (redm/reds double-buffered by sc&1 instead).
__global__ __launch_bounds__(512, 4) void iter_fused(const float* __restrict__ S,
                                                     const float* __restrict__ g,
                                                     const float* __restrict__ logb2,
                                                     float* __restrict__ f,
                                                     float* __restrict__ pm) {
    __shared__ float redm[2][2][8], reds[2][2][8];   // [sc&1][row-in-pair][wave]
    __shared__ float lbsh[CROWS];
    const int t = threadIdx.x;
    const int wv = t >> 6, lane = t & 63;
    const int chunk = blockIdx.x;
    const int r0 = chunk * CROWS;
    const int col0 = wv * 1024 + lane * 4;   // thread's base col (cols col0+it*256)

    // stage logb2 (tiny); visible to all after the first in-loop barrier
    if (t < CROWS) lbsh[t] = logb2[r0 + t];

    // g values for this thread's own columns — same 16 floats serve both phases
    float4 greg[4];
#pragma unroll
    for (int it = 0; it < 4; ++it)
        greg[it] = *(const float4*)(g + col0 + it * 256);

    // column accumulators for the thread's 16 owned columns
    float cm[4][4], cs[4][4];
#pragma unroll
    for (int it = 0; it < 4; ++it)
#pragma unroll
        for (int c = 0; c < 4; ++c) { cm[it][c] = -INFINITY; cs[it][c] = 0.0f; }

    const float* Sb = S + (size_t)r0 * NR + col0;

    // prologue: load rows 0,1 into bva
    float4 bva[8], bvb[8];
#pragma unroll
    for (int it = 0; it < 4; ++it) {
        bva[it]     = *(const float4*)(Sb + (size_t)0 * NR + it * 256);
        bva[4 + it] = *(const float4*)(Sb + (size_t)1 * NR + it * 256);
    }

    float fmine = 0.0f;
#pragma unroll
    for (int sc = 0; sc < NSUB; ++sc) {
        float4* cur = (sc & 1) ? bvb : bva;   // static after full unroll
        float4* nxt = (sc & 1) ? bva : bvb;
        // issue next sub-chunk's loads NOW; they retire during compute+barrier
        if (sc + 1 < NSUB) {
#pragma unroll
            for (int it = 0; it < 4; ++it) {
                nxt[it]     = *(const float4*)(Sb + (size_t)(2 * sc + 2) * NR + it * 256);
                nxt[4 + it] = *(const float4*)(Sb + (size_t)(2 * sc + 3) * NR + it * 256);
            }
        }

        // ---- phase 1: per-wave row-LSE partials over own segment, both rows ----
        float m0 = -INFINITY, s0 = 0.0f, m1 = -INFINITY, s1 = 0.0f;
#pragma unroll
        for (int it = 0; it < 4; ++it) {
            float4 v = cur[it], gv = greg[it];
            lse_upd4(m0, s0, v.x + gv.x, v.y + gv.y, v.z + gv.z, v.w + gv.w);
        }
#pragma unroll
        for (int it = 0; it < 4; ++it) {
            float4 v = cur[4 + it], gv = greg[it];
            lse_upd4(m1, s1, v.x + gv.x, v.y + gv.y, v.z + gv.z, v.w + gv.w);
        }
#pragma unroll
        for (int off = 32; off > 0; off >>= 1) {
            float a = __shfl_xor(m0, off), b = __shfl_xor(s0, off);
            lse_comb2(m0, s0, a, b);
            float c = __shfl_xor(m1, off), d = __shfl_xor(s1, off);
            lse_comb2(m1, s1, c, d);
        }
        const int pb = sc & 1;
        if (lane == 0) {
            redm[pb][0][wv] = m0; reds[pb][0][wv] = s0;
            redm[pb][1][wv] = m1; reds[pb][1][wv] = s1;
        }
        // raw barrier: drain LDS writes only — global loads stay IN FLIGHT
        asm volatile("s_waitcnt lgkmcnt(0)" ::: "memory");
        __builtin_amdgcn_s_barrier();

        // ---- combine 8 wave partials per row (redundant across threads) ----
        float M0 = redm[pb][0][0], Sm0 = reds[pb][0][0];
        lse_comb2(M0, Sm0, redm[pb][0][1], reds[pb][0][1]);
        float Ma = redm[pb][0][2], Sa = reds[pb][0][2];
        lse_comb2(Ma, Sa, redm[pb][0][3], reds[pb][0][3]);
        float Mb = redm[pb][0][4], Sb2 = reds[pb][0][4];
        lse_comb2(Mb, Sb2, redm[pb][0][5], reds[pb][0][5]);
        float Mc = redm[pb][0][6], Sc = reds[pb][0][6];
        lse_comb2(Mc, Sc, redm[pb][0][7], reds[pb][0][7]);
        lse_comb2(M0, Sm0, Ma, Sa);
        lse_comb2(Mb, Sb2, Mc, Sc);
        lse_comb2(M0, Sm0, Mb, Sb2);
        float N0 = redm[pb][1][0], Tn0 = reds[pb][1][0];
        lse_comb2(N0, Tn0, redm[pb][1][1], reds[pb][1][1]);
        float Na = redm[pb][1][2], Ta = reds[pb][1][2];
        lse_comb2(Na, Ta, redm[pb][1][3], reds[pb][1][3]);
        float Nb = redm[pb][1][4], Tb = reds[pb][1][4];
        lse_comb2(Nb, Tb, redm[pb][1][5], reds[pb][1][5]);
        float Nc = redm[pb][1][6], Tc = reds[pb][1][6];
        lse_comb2(Nc, Tc, redm[pb][1][7], reds[pb][1][7]);
        lse_comb2(N0, Tn0, Na, Ta);
        lse_comb2(Nb, Tb, Nc, Tc);
        lse_comb2(N0, Tn0, Nb, Tb);

        const float fr0 = lbsh[2 * sc + 0] - (M0 + flog2(Sm0));
        const float fr1 = lbsh[2 * sc + 1] - (N0 + flog2(Tn0));
        if (t == 2 * sc)     fmine = fr0;
        if (t == 2 * sc + 1) fmine = fr1;

        // ---- phase 2: column update over own 16 cols, both rows (same regs) ----
#pragma unroll
        for (int it = 0; it < 4; ++it) {
            float4 a = cur[it], b = cur[4 + it];
            lse_upd2(cm[it][0], cs[it][0], a.x + fr0, b.x + fr1);
            lse_upd2(cm[it][1], cs[it][1], a.y + fr0, b.y + fr1);
            lse_upd2(cm[it][2], cs[it][2], a.z + fr0, b.z + fr1);
            lse_upd2(cm[it][3], cs[it][3], a.w + fr0, b.w + fr1);
        }
        // no barrier B: redm double-buffer makes next write race-free, and no
        // shared S buffer exists to protect.
    }
    if (t < CROWS) f[r0 + t] = fmine;

    // write column partials for this chunk as a single float L = m + log2(s)
#pragma unroll
    for (int it = 0; it < 4; ++it) {
        float4 L;
        L.x = cm[it][0] + flog2(cs[it][0]);
        L.y = cm[it][1] + flog2(cs[it][1]);
        L.z = cm[it][2] + flog2(cs[it][2]);
        L.w = cm[it][3] + flog2(cs[it][3]);
        *(float4*)&pm[(size_t)chunk * NR + col0 + it * 256] = L;
    }
}

// ---------------- combine partials -> g (256 blocks, two-level LSE) ----------------
__global__ __launch_bounds__(256) void col_combine(const float* __restrict__ pm,
                                                   float* __restrict__ g,
                                                   float log_a2) {
    __shared__ float Lsh[8][32];
    const int cl = threadIdx.x & 31;       // column within block
    const int gp = threadIdx.x >> 5;       // chunk group (0..7), 64 chunks each
    const int col = blockIdx.x * 32 + cl;
    float m = -INFINITY, s = 0.0f;
#pragma unroll
    for (int ch = gp * 64; ch < gp * 64 + 64; ch += 4) {
        float l0 = pm[(size_t)(ch + 0) * NR + col];
        float l1 = pm[(size_t)(ch + 1) * NR + col];
        float l2 = pm[(size_t)(ch + 2) * NR + col];
        float l3 = pm[(size_t)(ch + 3) * NR + col];
        lse_upd4(m, s, l0, l1, l2, l3);
    }
    Lsh[gp][cl] = m + flog2(s);
    __syncthreads();
    if (gp == 0) {
        float mm = -INFINITY, ss = 0.0f;
        lse_upd4(mm, ss, Lsh[0][cl], Lsh[1][cl], Lsh[2][cl], Lsh[3][cl]);
        lse_upd4(mm, ss, Lsh[4][cl], Lsh[5][cl], Lsh[6][cl], Lsh[7][cl]);
        g[col] = log_a2 - (mm + flog2(ss));
    }
}

// ---------------- T = exp2(f + S + g), in place; global sum == 1 analytically ------
// note: no __restrict__ on S/out — they alias (in-place)
__global__ __launch_bounds__(256) void write_pass(const float* S,
                                                  const float* __restrict__ f,
                                                  const float* __restrict__ g,
                                                  float* out) {
    const int wv = threadIdx.x >> 6, lane = threadIdx.x & 63;
    const int row = blockIdx.x * 4 + wv;
    const float fi = f[row];
    const float4* Sr = (const float4*)(S + (size_t)row * NR);
    const float4* gr = (const float4*)g;
    float4* Or = (float4*)(out + (size_t)row * NR);
#pragma unroll 4
    for (int it = 0; it < NR / 256; ++it) {
        const int idx = it * 64 + lane;
        float4 sv = Sr[idx];
        float4 gv = gr[idx];
        float4 o;
        o.x = fexp2(fi + sv.x + gv.x);
        o.y = fexp2(fi + sv.y + gv.y);
        o.z = fexp2(fi + sv.z + gv.z);
        o.w = fexp2(fi + sv.w + gv.w);
        Or[idx] = o;
    }
}

extern "C" void kernel_launch(void* const* d_in, const int* in_sizes, int n_in,
                              void* d_out, int out_size, void* d_ws, size_t ws_size,
                              hipStream_t stream) {
    (void)in_sizes; (void)n_in; (void)out_size; (void)ws_size;
    const float* A  = (const float*)d_in[0];
    const float* Tk = (const float*)d_in[1];
    const float* Wq = (const float*)d_in[2];
    const float* bq = (const float*)d_in[3];
    const float* Wk = (const float*)d_in[4];
    const float* bk = (const float*)d_in[5];
    const float* W1 = (const float*)d_in[6];
    const float* b1 = (const float*)d_in[7];
    const float* W2 = (const float*)d_in[8];
    const float* b2 = (const float*)d_in[9];
    float* S  = (float*)d_out;           // 8192x8192 base-2 log_K lives in d_out
    float* ws = (float*)d_ws;
    float* qn     = ws; ws += NR;
    float* kn     = ws; ws += NR;
    float* logb2  = ws; ws += NR;
    float* logits = ws; ws += NR;
    float* f      = ws; ws += NR;
    float* g      = ws; ws += NR;
    float* pm     = ws; ws += (size_t)NBLK * NR;   // 16 MB
    float* q      = ws; ws += (size_t)NR * DIM;    // 8 MB
    float* k      = ws; ws += (size_t)NR * DIM;    // 8 MB
    // bf16 split arrays overlay pm (16.78 MB == 4 x NR*DIM ushorts): they are
    // dead once dist_mfma finishes, before the first iter_fused writes pm.
    ushort_t* qh = (ushort_t*)pm;
    ushort_t* ql = qh + (size_t)NR * DIM;
    ushort_t* kh = ql + (size_t)NR * DIM;
    ushort_t* kl = kh + (size_t)NR * DIM;

    const float log_a2 = -13.0f; // log2(1/8192 + 1e-20)

    init_zero<<<32, 256, 0, stream>>>(g);
    gemm_qk<<<dim3(128, 4), 256, 0, stream>>>(A, Wq, bq, q);
    gemm_qk<<<dim3(128, 4), 256, 0, stream>>>(Tk, Wk, bk, k);
    row_norm<<<NR, 64, 0, stream>>>(q, qn);
    row_norm<<<NR, 64, 0, stream>>>(k, kn);
    split_bf16<<<NR * DIM / 1024, 256, 0, stream>>>(q, qh, ql);
    split_bf16<<<NR * DIM / 1024, 256, 0, stream>>>(k, kh, kl);
    mlp_logits<<<NR, 128, 0, stream>>>(A, W1, b1, W2, b2, logits);
    softmax_logb<<<1, 1024, 0, stream>>>(logits, logb2);
    dist_mfma<<<dim3(64, 64), 256, 0, stream>>>(qh, ql, kh, kl, qn, kn, S);
    for (int it = 0; it < 50; ++it) {
        iter_fused<<<NBLK, 512, 0, stream>>>(S, g, logb2, f, pm);
        col_combine<<<NR / 32, 256, 0, stream>>>(pm, g, log_a2);
    }
    write_pass<<<NR / 4, 256, 0, stream>>>(S, f, g, S);
}

// Round 3
// 14033.734 us; speedup vs baseline: 1.0381x; 1.0381x over previous
//
#include <hip/hip_runtime.h>
#include <math.h>

#define NR 8192      // NA == NT
#define DIM 256
#define NBLK 512     // fused-kernel blocks == column-partial chunks (2 per CU)
#define CROWS 16     // rows per chunk
#define NSUB 8       // sub-chunks per chunk (2 rows each, reg ping-pong)
// 10 * log2(e): converts distances directly into base-2 log domain
#define SCALE2 14.426950408889634f

typedef unsigned short ushort_t;
typedef __attribute__((ext_vector_type(8))) short bfrag;   // 8 bf16 (4 VGPRs)
typedef __attribute__((ext_vector_type(4))) float facc;    // 4 fp32 acc

// v_exp_f32 / v_log_f32 are base-2 natively — use them raw
__device__ __forceinline__ float fexp2(float x) {
#if __has_builtin(__builtin_amdgcn_exp2f)
    return __builtin_amdgcn_exp2f(x);
#else
    return exp2f(x);
#endif
}
__device__ __forceinline__ float flog2(float x) {
#if __has_builtin(__builtin_amdgcn_logf)
    return __builtin_amdgcn_logf(x);
#else
    return log2f(x);
#endif
}

// base-2 online LSE combine
__device__ __forceinline__ void lse_comb2(float& m, float& s, float mo, float so) {
    float nm = fmaxf(m, mo);
    s = s * fexp2(m - nm) + so * fexp2(mo - nm);
    m = nm;
}

// grouped-4 online LSE update (1 tree-max + 1 correction exp per 4 values)
__device__ __forceinline__ void lse_upd4(float& m, float& s,
                                         float v0, float v1, float v2, float v3) {
    float m4 = fmaxf(fmaxf(v0, v1), fmaxf(v2, v3));
    float nm = fmaxf(m, m4);
    float e = fexp2(v0 - nm) + fexp2(v1 - nm) + fexp2(v2 - nm) + fexp2(v3 - nm);
    s = fmaf(s, fexp2(m - nm), e);
    m = nm;
}

// grouped-2 online LSE update
__device__ __forceinline__ void lse_upd2(float& m, float& s, float v0, float v1) {
    float m2 = fmaxf(v0, v1);
    float nm = fmaxf(m, m2);
    float e = fexp2(v0 - nm) + fexp2(v1 - nm);
    s = fmaf(s, fexp2(m - nm), e);
    m = nm;
}

// RNE float -> bf16 bits (manual: deterministic, no API variance)
__device__ __forceinline__ ushort_t f2bf(float x) {
    unsigned u = __float_as_uint(x);
    u += 0x7FFFu + ((u >> 16) & 1u);
    return (ushort_t)(u >> 16);
}
__device__ __forceinline__ float bf2f(ushort_t b) {
    return __uint_as_float(((unsigned)b) << 16);
}

// ---------------- init ----------------
__global__ void init_zero(float* __restrict__ g) {
    int t = blockIdx.x * 256 + threadIdx.x;
    if (t < NR) g[t] = 0.0f;
}

// ---------------- out[M,DIM] = A[M,DIM] @ W[DIM,DIM] + bias ----------------
__global__ __launch_bounds__(256) void gemm_qk(const float* __restrict__ A,
                                               const float* __restrict__ W,
                                               const float* __restrict__ bias,
                                               float* __restrict__ out) {
    __shared__ float As[16][68];
    __shared__ float Ws[16][68];
    const int t  = threadIdx.x;
    const int r0 = blockIdx.x * 64;
    const int c0 = blockIdx.y * 64;
    const int ty = t >> 4, tx = t & 15;
    const int arow = t >> 2;
    const int ak   = (t & 3) * 4;
    const int wrow = t >> 4;
    const int wcol = (t & 15) * 4;
    float acc[4][4] = {};
    for (int k0 = 0; k0 < DIM; k0 += 16) {
        float4 av = *(const float4*)(A + (size_t)(r0 + arow) * DIM + k0 + ak);
        float4 wv = *(const float4*)(W + (size_t)(k0 + wrow) * DIM + c0 + wcol);
        __syncthreads();
        As[ak + 0][arow] = av.x; As[ak + 1][arow] = av.y;
        As[ak + 2][arow] = av.z; As[ak + 3][arow] = av.w;
        *(float4*)&Ws[wrow][wcol] = wv;
        __syncthreads();
#pragma unroll
        for (int kk = 0; kk < 16; ++kk) {
            float4 a = *(const float4*)&As[kk][ty * 4];
            float4 b = *(const float4*)&Ws[kk][tx * 4];
            float aa[4] = {a.x, a.y, a.z, a.w};
            float bb[4] = {b.x, b.y, b.z, b.w};
#pragma unroll
            for (int i = 0; i < 4; ++i)
#pragma unroll
                for (int j = 0; j < 4; ++j)
                    acc[i][j] = fmaf(aa[i], bb[j], acc[i][j]);
        }
    }
#pragma unroll
    for (int i = 0; i < 4; ++i) {
        float4 o;
        o.x = acc[i][0] + bias[c0 + tx * 4 + 0];
        o.y = acc[i][1] + bias[c0 + tx * 4 + 1];
        o.z = acc[i][2] + bias[c0 + tx * 4 + 2];
        o.w = acc[i][3] + bias[c0 + tx * 4 + 3];
        *(float4*)(out + (size_t)(r0 + ty * 4 + i) * DIM + c0 + tx * 4) = o;
    }
}

// ---------------- row squared norms ----------------
__global__ __launch_bounds__(64) void row_norm(const float* __restrict__ x,
                                               float* __restrict__ out) {
    const int row = blockIdx.x, lane = threadIdx.x;
    float4 v = *(const float4*)(x + (size_t)row * DIM + lane * 4);
    float s = v.x * v.x + v.y * v.y + v.z * v.z + v.w * v.w;
#pragma unroll
    for (int off = 32; off > 0; off >>= 1) s += __shfl_xor(s, off);
    if (lane == 0) out[row] = s;
}

// ---------------- split fp32 -> bf16 hi + bf16 lo (lo = bf16(x - hi)) ----------------
__global__ __launch_bounds__(256) void split_bf16(const float* __restrict__ x,
                                                  ushort_t* __restrict__ hi,
                                                  ushort_t* __restrict__ lo) {
    const int idx = (blockIdx.x * 256 + threadIdx.x) * 4;
    float4 v = *(const float4*)(x + idx);
    ushort_t h0 = f2bf(v.x), h1 = f2bf(v.y), h2 = f2bf(v.z), h3 = f2bf(v.w);
    ushort4 hv = make_ushort4(h0, h1, h2, h3);
    ushort4 lv = make_ushort4(f2bf(v.x - bf2f(h0)), f2bf(v.y - bf2f(h1)),
                              f2bf(v.z - bf2f(h2)), f2bf(v.w - bf2f(h3)));
    *(ushort4*)(hi + idx) = hv;
    *(ushort4*)(lo + idx) = lv;
}

// ---------------- S = SCALE2*(qn_i + kn_j - 2*q_i.k_j) via split-bf16 MFMA ----------
__global__ __launch_bounds__(256) void dist_mfma(const ushort_t* __restrict__ qh,
                                                 const ushort_t* __restrict__ ql,
                                                 const ushort_t* __restrict__ kh,
                                                 const ushort_t* __restrict__ kl,
                                                 const float* __restrict__ qn,
                                                 const float* __restrict__ kn,
                                                 float* __restrict__ S) {
    const int t = threadIdx.x;
    const int wv = t >> 6, lane = t & 63;
    const int r0 = blockIdx.y * 128 + (wv >> 1) * 64;
    const int c0 = blockIdx.x * 128 + (wv & 1) * 64;
    const int fr = lane & 15;       // row (A) / col (B) within 16x16 tile
    const int fq = lane >> 4;       // quad -> k-subrange / C-row group
    facc acc[4][4];
#pragma unroll
    for (int i = 0; i < 4; ++i)
#pragma unroll
        for (int j = 0; j < 4; ++j) acc[i][j] = (facc){0.f, 0.f, 0.f, 0.f};

    for (int k0 = 0; k0 < DIM; k0 += 32) {
        const int ks = k0 + fq * 8;
        bfrag ah[4], al[4], bh[4], bl[4];
#pragma unroll
        for (int mi = 0; mi < 4; ++mi) {
            const size_t ao = (size_t)(r0 + mi * 16 + fr) * DIM + ks;
            ah[mi] = *(const bfrag*)(qh + ao);
            al[mi] = *(const bfrag*)(ql + ao);
        }
#pragma unroll
        for (int ni = 0; ni < 4; ++ni) {
            const size_t bo = (size_t)(c0 + ni * 16 + fr) * DIM + ks;
            bh[ni] = *(const bfrag*)(kh + bo);
            bl[ni] = *(const bfrag*)(kl + bo);
        }
#pragma unroll
        for (int mi = 0; mi < 4; ++mi)
#pragma unroll
            for (int ni = 0; ni < 4; ++ni) {
                acc[mi][ni] = __builtin_amdgcn_mfma_f32_16x16x32_bf16(ah[mi], bh[ni], acc[mi][ni], 0, 0, 0);
                acc[mi][ni] = __builtin_amdgcn_mfma_f32_16x16x32_bf16(ah[mi], bl[ni], acc[mi][ni], 0, 0, 0);
                acc[mi][ni] = __builtin_amdgcn_mfma_f32_16x16x32_bf16(al[mi], bh[ni], acc[mi][ni], 0, 0, 0);
                acc[mi][ni] = __builtin_amdgcn_mfma_f32_16x16x32_bf16(al[mi], bl[ni], acc[mi][ni], 0, 0, 0);
            }
    }
    // epilogue: S[row][col] = (qn + kn - 2*dot) * SCALE2
#pragma unroll
    for (int mi = 0; mi < 4; ++mi) {
        float qnr[4];
#pragma unroll
        for (int r = 0; r < 4; ++r) qnr[r] = qn[r0 + mi * 16 + fq * 4 + r];
#pragma unroll
        for (int ni = 0; ni < 4; ++ni) {
            const int col = c0 + ni * 16 + fr;
            const float knc = kn[col];
#pragma unroll
            for (int r = 0; r < 4; ++r) {
                const int row = r0 + mi * 16 + fq * 4 + r;
                S[(size_t)row * NR + col] = (qnr[r] + knc - 2.0f * acc[mi][ni][r]) * SCALE2;
            }
        }
    }
}

// ---------------- MLP logits: relu(A@W1+b1)@W2 + b2 ----------------
__global__ __launch_bounds__(128) void mlp_logits(const float* __restrict__ A,
                                                  const float* __restrict__ W1,
                                                  const float* __restrict__ b1,
                                                  const float* __restrict__ W2,
                                                  const float* __restrict__ b2,
                                                  float* __restrict__ logits) {
    __shared__ float ar[DIM];
    __shared__ float red[2];
    const int t = threadIdx.x;
    const int row = blockIdx.x;
    *(float2*)&ar[t * 2] = *(const float2*)(A + (size_t)row * DIM + t * 2);
    __syncthreads();
    float h = b1[t];
#pragma unroll 8
    for (int kk = 0; kk < DIM; ++kk) h = fmaf(ar[kk], W1[kk * 128 + t], h);
    float val = fmaxf(h, 0.0f) * W2[t];
#pragma unroll
    for (int off = 32; off > 0; off >>= 1) val += __shfl_xor(val, off);
    if ((t & 63) == 0) red[t >> 6] = val;
    __syncthreads();
    if (t == 0) logits[row] = red[0] + red[1] + b2[0];
}

// ---------------- softmax over 8192 logits -> log2(b + 1e-20) ----------------
__global__ __launch_bounds__(1024) void softmax_logb(const float* __restrict__ logits,
                                                     float* __restrict__ logb2) {
    __shared__ float redm[16], reds[16];
    const int t = threadIdx.x;
    float l[8];
    float m = -INFINITY;
#pragma unroll
    for (int i = 0; i < 8; ++i) { l[i] = logits[i * 1024 + t]; m = fmaxf(m, l[i]); }
#pragma unroll
    for (int off = 32; off > 0; off >>= 1) m = fmaxf(m, __shfl_xor(m, off));
    if ((t & 63) == 0) redm[t >> 6] = m;
    __syncthreads();
    if (t < 64) {
        float v = (t < 16) ? redm[t] : -INFINITY;
#pragma unroll
        for (int off = 8; off > 0; off >>= 1) v = fmaxf(v, __shfl_xor(v, off));
        if (t == 0) redm[0] = v;
    }
    __syncthreads();
    m = redm[0];
    float s = 0.0f;
#pragma unroll
    for (int i = 0; i < 8; ++i) s += __expf(l[i] - m);
#pragma unroll
    for (int off = 32; off > 0; off >>= 1) s += __shfl_xor(s, off);
    if ((t & 63) == 0) reds[t >> 6] = s;
    __syncthreads();
    if (t < 64) {
        float v = (t < 16) ? reds[t] : 0.0f;
#pragma unroll
        for (int off = 8; off > 0; off >>= 1) v += __shfl_xor(v, off);
        if (t == 0) reds[0] = v;
    }
    __syncthreads();
    s = reds[0];
    float invs = 1.0f / s;
#pragma unroll
    for (int i = 0; i < 8; ++i)
        logb2[i * 1024 + t] = log2f(__expf(l[i] - m) * invs + 1e-20f);
}

// ---------------- fused iteration: wave-aligned, REGISTER-direct, LDS-free S -------
// Each wave owns a 1024-col segment for ALL 16 rows of its chunk. Thread t owns
// cols {wv*1024 + lane*4 + it*256}. Sub-chunk = 2 rows loaded straight into
// registers (8x global_load_dwordx4), ping-pong bva/bvb issued one sub-chunk
// ahead. CRITICAL (R2 lesson, rule #20): the ping-pong MUST be expressed with
// static array names (inlined lambda called twice), never a runtime-selected
// pointer — otherwise bva/bvb/cm/cs land in scratch (R2: 519 MB spill writes).
// g lives in LDS (32 KB, read-only after prologue) to keep VGPRs < 128 for
// 2 blocks/CU. One raw (non-draining) barrier per sub-chunk; redm/reds double-
// buffered by sc&1 (write[sc&1] -> barrier -> read[sc&1]; next write of the
// same buffer is separated by the sc+1 barrier => race-free, verified R2).
__global__ __launch_bounds__(512, 4) void iter_fused(const float* __restrict__ S,
                                                     const float* __restrict__ g,
                                                     const float* __restrict__ logb2,
                                                     float* __restrict__ f,
                                                     float* __restrict__ pm) {
    __shared__ float gsh[NR];                        // 32 KB, staged once
    __shared__ float redm[2][2][8], reds[2][2][8];   // [sc&1][row-in-pair][wave]
    __shared__ float lbsh[CROWS];
    const int t = threadIdx.x;
    const int wv = t >> 6, lane = t & 63;
    const int chunk = blockIdx.x;
    const int r0 = chunk * CROWS;
    const int col0 = wv * 1024 + lane * 4;   // thread's base col (cols col0+it*256)

    if (t < CROWS) lbsh[t] = logb2[r0 + t];
    // stage g into LDS: 512 threads x 4 float4, coalesced
#pragma unroll
    for (int it = 0; it < 4; ++it) {
        float4 gv = *(const float4*)(g + t * 4 + it * 2048);
        *(float4*)&gsh[t * 4 + it * 2048] = gv;
    }

    // column accumulators for the thread's 16 owned columns
    float cm[4][4], cs[4][4];
#pragma unroll
    for (int it = 0; it < 4; ++it)
#pragma unroll
        for (int c = 0; c < 4; ++c) { cm[it][c] = -INFINITY; cs[it][c] = 0.0f; }

    const float* Sb = S + (size_t)r0 * NR + col0;
    float fmine = 0.0f;

    __syncthreads();   // gsh/lbsh ready (full drain OK: prologue only)

    // prologue: rows 0,1 into bva (issued AFTER the draining barrier)
    float4 bva[8], bvb[8];
#pragma unroll
    for (int it = 0; it < 4; ++it) {
        bva[it]     = *(const float4*)(Sb + (size_t)0 * NR + it * 256);
        bva[4 + it] = *(const float4*)(Sb + (size_t)1 * NR + it * 256);
    }

    // sub-chunk body: all array indices compile-time-constant after inlining
    auto subchunk = [&](int sc, int pb, float4 (&cur)[8], float4 (&nxt)[8])
        __attribute__((always_inline)) {
        // issue next sub-chunk's loads NOW; retire during compute + barrier
        if (sc + 1 < NSUB) {
#pragma unroll
            for (int it = 0; it < 4; ++it) {
                nxt[it]     = *(const float4*)(Sb + (size_t)(2 * sc + 2) * NR + it * 256);
                nxt[4 + it] = *(const float4*)(Sb + (size_t)(2 * sc + 3) * NR + it * 256);
            }
        }

        // ---- phase 1: per-wave row-LSE partials over own segment, both rows ----
        float m0 = -INFINITY, s0 = 0.0f, m1 = -INFINITY, s1 = 0.0f;
#pragma unroll
        for (int it = 0; it < 4; ++it) {
            float4 gv = *(const float4*)&gsh[col0 + it * 256];  // shared by both rows
            float4 v = cur[it];
            lse_upd4(m0, s0, v.x + gv.x, v.y + gv.y, v.z + gv.z, v.w + gv.w);
            float4 w = cur[4 + it];
            lse_upd4(m1, s1, w.x + gv.x, w.y + gv.y, w.z + gv.z, w.w + gv.w);
        }
#pragma unroll
        for (int off = 32; off > 0; off >>= 1) {
            float a = __shfl_xor(m0, off), b = __shfl_xor(s0, off);
            lse_comb2(m0, s0, a, b);
            float c = __shfl_xor(m1, off), d = __shfl_xor(s1, off);
            lse_comb2(m1, s1, c, d);
        }
        if (lane == 0) {
            redm[pb][0][wv] = m0; reds[pb][0][wv] = s0;
            redm[pb][1][wv] = m1; reds[pb][1][wv] = s1;
        }
        // raw barrier: drain LDS only — global loads stay IN FLIGHT
        asm volatile("s_waitcnt lgkmcnt(0)" ::: "memory");
        __builtin_amdgcn_s_barrier();

        // ---- combine 8 wave partials per row (redundant across threads) ----
        float M0 = redm[pb][0][0], Sm0 = reds[pb][0][0];
        lse_comb2(M0, Sm0, redm[pb][0][1], reds[pb][0][1]);
        float Ma = redm[pb][0][2], Sa = reds[pb][0][2];
        lse_comb2(Ma, Sa, redm[pb][0][3], reds[pb][0][3]);
        float Mb = redm[pb][0][4], Sb2 = reds[pb][0][4];
        lse_comb2(Mb, Sb2, redm[pb][0][5], reds[pb][0][5]);
        float Mc = redm[pb][0][6], Sc = reds[pb][0][6];
        lse_comb2(Mc, Sc, redm[pb][0][7], reds[pb][0][7]);
        lse_comb2(M0, Sm0, Ma, Sa);
        lse_comb2(Mb, Sb2, Mc, Sc);
        lse_comb2(M0, Sm0, Mb, Sb2);
        float N0 = redm[pb][1][0], Tn0 = reds[pb][1][0];
        lse_comb2(N0, Tn0, redm[pb][1][1], reds[pb][1][1]);
        float Na = redm[pb][1][2], Ta = reds[pb][1][2];
        lse_comb2(Na, Ta, redm[pb][1][3], reds[pb][1][3]);
        float Nb = redm[pb][1][4], Tb = reds[pb][1][4];
        lse_comb2(Nb, Tb, redm[pb][1][5], reds[pb][1][5]);
        float Nc = redm[pb][1][6], Tc = reds[pb][1][6];
        lse_comb2(Nc, Tc, redm[pb][1][7], reds[pb][1][7]);
        lse_comb2(N0, Tn0, Na, Ta);
        lse_comb2(Nb, Tb, Nc, Tc);
        lse_comb2(N0, Tn0, Nb, Tb);

        const float fr0 = lbsh[2 * sc + 0] - (M0 + flog2(Sm0));
        const float fr1 = lbsh[2 * sc + 1] - (N0 + flog2(Tn0));
        if (t == 2 * sc)     fmine = fr0;
        if (t == 2 * sc + 1) fmine = fr1;

        // ---- phase 2: column update over own 16 cols, both rows (same regs) ----
#pragma unroll
        for (int it = 0; it < 4; ++it) {
            float4 a = cur[it], b = cur[4 + it];
            lse_upd2(cm[it][0], cs[it][0], a.x + fr0, b.x + fr1);
            lse_upd2(cm[it][1], cs[it][1], a.y + fr0, b.y + fr1);
            lse_upd2(cm[it][2], cs[it][2], a.z + fr0, b.z + fr1);
            lse_upd2(cm[it][3], cs[it][3], a.w + fr0, b.w + fr1);
        }
    };

#pragma unroll
    for (int scp = 0; scp < NSUB; scp += 2) {
        subchunk(scp,     0, bva, bvb);
        subchunk(scp + 1, 1, bvb, bva);
    }

    if (t < CROWS) f[r0 + t] = fmine;

    // write column partials for this chunk as a single float L = m + log2(s)
#pragma unroll
    for (int it = 0; it < 4; ++it) {
        float4 L;
        L.x = cm[it][0] + flog2(cs[it][0]);
        L.y = cm[it][1] + flog2(cs[it][1]);
        L.z = cm[it][2] + flog2(cs[it][2]);
        L.w = cm[it][3] + flog2(cs[it][3]);
        *(float4*)&pm[(size_t)chunk * NR + col0 + it * 256] = L;
    }
}

// ---------------- combine partials -> g (256 blocks, two-level LSE) ----------------
__global__ __launch_bounds__(256) void col_combine(const float* __restrict__ pm,
                                                   float* __restrict__ g,
                                                   float log_a2) {
    __shared__ float Lsh[8][32];
    const int cl = threadIdx.x & 31;       // column within block
    const int gp = threadIdx.x >> 5;       // chunk group (0..7), 64 chunks each
    const int col = blockIdx.x * 32 + cl;
    float m = -INFINITY, s = 0.0f;
#pragma unroll
    for (int ch = gp * 64; ch < gp * 64 + 64; ch += 4) {
        float l0 = pm[(size_t)(ch + 0) * NR + col];
        float l1 = pm[(size_t)(ch + 1) * NR + col];
        float l2 = pm[(size_t)(ch + 2) * NR + col];
        float l3 = pm[(size_t)(ch + 3) * NR + col];
        lse_upd4(m, s, l0, l1, l2, l3);
    }
    Lsh[gp][cl] = m + flog2(s);
    __syncthreads();
    if (gp == 0) {
        float mm = -INFINITY, ss = 0.0f;
        lse_upd4(mm, ss, Lsh[0][cl], Lsh[1][cl], Lsh[2][cl], Lsh[3][cl]);
        lse_upd4(mm, ss, Lsh[4][cl], Lsh[5][cl], Lsh[6][cl], Lsh[7][cl]);
        g[col] = log_a2 - (mm + flog2(ss));
    }
}

// ---------------- T = exp2(f + S + g), in place; global sum == 1 analytically ------
// note: no __restrict__ on S/out — they alias (in-place)
__global__ __launch_bounds__(256) void write_pass(const float* S,
                                                  const float* __restrict__ f,
                                                  const float* __restrict__ g,
                                                  float* out) {
    const int wv = threadIdx.x >> 6, lane = threadIdx.x & 63;
    const int row = blockIdx.x * 4 + wv;
    const float fi = f[row];
    const float4* Sr = (const float4*)(S + (size_t)row * NR);
    const float4* gr = (const float4*)g;
    float4* Or = (float4*)(out + (size_t)row * NR);
#pragma unroll 4
    for (int it = 0; it < NR / 256; ++it) {
        const int idx = it * 64 + lane;
        float4 sv = Sr[idx];
        float4 gv = gr[idx];
        float4 o;
        o.x = fexp2(fi + sv.x + gv.x);
        o.y = fexp2(fi + sv.y + gv.y);
        o.z = fexp2(fi + sv.z + gv.z);
        o.w = fexp2(fi + sv.w + gv.w);
        Or[idx] = o;
    }
}

extern "C" void kernel_launch(void* const* d_in, const int* in_sizes, int n_in,
                              void* d_out, int out_size, void* d_ws, size_t ws_size,
                              hipStream_t stream) {
    (void)in_sizes; (void)n_in; (void)out_size; (void)ws_size;
    const float* A  = (const float*)d_in[0];
    const float* Tk = (const float*)d_in[1];
    const float* Wq = (const float*)d_in[2];
    const float* bq = (const float*)d_in[3];
    const float* Wk = (const float*)d_in[4];
    const float* bk = (const float*)d_in[5];
    const float* W1 = (const float*)d_in[6];
    const float* b1 = (const float*)d_in[7];
    const float* W2 = (const float*)d_in[8];
    const float* b2 = (const float*)d_in[9];
    float* S  = (float*)d_out;           // 8192x8192 base-2 log_K lives in d_out
    float* ws = (float*)d_ws;
    float* qn     = ws; ws += NR;
    float* kn     = ws; ws += NR;
    float* logb2  = ws; ws += NR;
    float* logits = ws; ws += NR;
    float* f      = ws; ws += NR;
    float* g      = ws; ws += NR;
    float* pm     = ws; ws += (size_t)NBLK * NR;   // 16 MB
    float* q      = ws; ws += (size_t)NR * DIM;    // 8 MB
    float* k      = ws; ws += (size_t)NR * DIM;    // 8 MB
    // bf16 split arrays overlay pm (16.78 MB == 4 x NR*DIM ushorts): they are
    // dead once dist_mfma finishes, before the first iter_fused writes pm.
    ushort_t* qh = (ushort_t*)pm;
    ushort_t* ql = qh + (size_t)NR * DIM;
    ushort_t* kh = ql + (size_t)NR * DIM;
    ushort_t* kl = kh + (size_t)NR * DIM;

    const float log_a2 = -13.0f; // log2(1/8192 + 1e-20)

    init_zero<<<32, 256, 0, stream>>>(g);
    gemm_qk<<<dim3(128, 4), 256, 0, stream>>>(A, Wq, bq, q);
    gemm_qk<<<dim3(128, 4), 256, 0, stream>>>(Tk, Wk, bk, k);
    row_norm<<<NR, 64, 0, stream>>>(q, qn);
    row_norm<<<NR, 64, 0, stream>>>(k, kn);
    split_bf16<<<NR * DIM / 1024, 256, 0, stream>>>(q, qh, ql);
    split_bf16<<<NR * DIM / 1024, 256, 0, stream>>>(k, kh, kl);
    mlp_logits<<<NR, 128, 0, stream>>>(A, W1, b1, W2, b2, logits);
    softmax_logb<<<1, 1024, 0, stream>>>(logits, logb2);
    dist_mfma<<<dim3(64, 64), 256, 0, stream>>>(qh, ql, kh, kl, qn, kn, S);
    for (int it = 0; it < 50; ++it) {
        iter_fused<<<NBLK, 512, 0, stream>>>(S, g, logb2, f, pm);
        col_combine<<<NR / 32, 256, 0, stream>>>(pm, g, log_a2);
    }
    write_pass<<<NR / 4, 256, 0, stream>>>(S, f, g, S);
}

// Round 4
// 13680.437 us; speedup vs baseline: 1.0649x; 1.0258x over previous
//
#include <hip/hip_runtime.h>
#include <math.h>

#define NR 8192      // NA == NT
#define DIM 256
#define NBLK 512     // fused-kernel blocks == column-partial chunks (2 per CU)
#define CROWS 16     // rows per chunk
#define NSUB 8       // sub-chunks per chunk (2 rows each, reg ping-pong)
// 10 * log2(e): converts distances directly into base-2 log domain
#define SCALE2 14.426950408889634f

typedef unsigned short ushort_t;
typedef __attribute__((ext_vector_type(8))) short bfrag;   // 8 bf16 (4 VGPRs)
typedef __attribute__((ext_vector_type(4))) float facc;    // 4 fp32 acc

// v_exp_f32 / v_log_f32 are base-2 natively — use them raw
__device__ __forceinline__ float fexp2(float x) {
#if __has_builtin(__builtin_amdgcn_exp2f)
    return __builtin_amdgcn_exp2f(x);
#else
    return exp2f(x);
#endif
}
__device__ __forceinline__ float flog2(float x) {
#if __has_builtin(__builtin_amdgcn_logf)
    return __builtin_amdgcn_logf(x);
#else
    return log2f(x);
#endif
}

// base-2 online LSE combine
__device__ __forceinline__ void lse_comb2(float& m, float& s, float mo, float so) {
    float nm = fmaxf(m, mo);
    s = s * fexp2(m - nm) + so * fexp2(mo - nm);
    m = nm;
}

// grouped-4 online LSE update (1 tree-max + 1 correction exp per 4 values)
__device__ __forceinline__ void lse_upd4(float& m, float& s,
                                         float v0, float v1, float v2, float v3) {
    float m4 = fmaxf(fmaxf(v0, v1), fmaxf(v2, v3));
    float nm = fmaxf(m, m4);
    float e = fexp2(v0 - nm) + fexp2(v1 - nm) + fexp2(v2 - nm) + fexp2(v3 - nm);
    s = fmaf(s, fexp2(m - nm), e);
    m = nm;
}

// grouped-2 online LSE update
__device__ __forceinline__ void lse_upd2(float& m, float& s, float v0, float v1) {
    float m2 = fmaxf(v0, v1);
    float nm = fmaxf(m, m2);
    float e = fexp2(v0 - nm) + fexp2(v1 - nm);
    s = fmaf(s, fexp2(m - nm), e);
    m = nm;
}

// RNE float -> bf16 bits (manual: deterministic, no API variance)
__device__ __forceinline__ ushort_t f2bf(float x) {
    unsigned u = __float_as_uint(x);
    u += 0x7FFFu + ((u >> 16) & 1u);
    return (ushort_t)(u >> 16);
}
__device__ __forceinline__ float bf2f(ushort_t b) {
    return __uint_as_float(((unsigned)b) << 16);
}

// ---------------- init ----------------
__global__ void init_zero(float* __restrict__ g) {
    int t = blockIdx.x * 256 + threadIdx.x;
    if (t < NR) g[t] = 0.0f;
}

// ---------------- out[M,DIM] = A[M,DIM] @ W[DIM,DIM] + bias ----------------
__global__ __launch_bounds__(256) void gemm_qk(const float* __restrict__ A,
                                               const float* __restrict__ W,
                                               const float* __restrict__ bias,
                                               float* __restrict__ out) {
    __shared__ float As[16][68];
    __shared__ float Ws[16][68];
    const int t  = threadIdx.x;
    const int r0 = blockIdx.x * 64;
    const int c0 = blockIdx.y * 64;
    const int ty = t >> 4, tx = t & 15;
    const int arow = t >> 2;
    const int ak   = (t & 3) * 4;
    const int wrow = t >> 4;
    const int wcol = (t & 15) * 4;
    float acc[4][4] = {};
    for (int k0 = 0; k0 < DIM; k0 += 16) {
        float4 av = *(const float4*)(A + (size_t)(r0 + arow) * DIM + k0 + ak);
        float4 wv = *(const float4*)(W + (size_t)(k0 + wrow) * DIM + c0 + wcol);
        __syncthreads();
        As[ak + 0][arow] = av.x; As[ak + 1][arow] = av.y;
        As[ak + 2][arow] = av.z; As[ak + 3][arow] = av.w;
        *(float4*)&Ws[wrow][wcol] = wv;
        __syncthreads();
#pragma unroll
        for (int kk = 0; kk < 16; ++kk) {
            float4 a = *(const float4*)&As[kk][ty * 4];
            float4 b = *(const float4*)&Ws[kk][tx * 4];
            float aa[4] = {a.x, a.y, a.z, a.w};
            float bb[4] = {b.x, b.y, b.z, b.w};
#pragma unroll
            for (int i = 0; i < 4; ++i)
#pragma unroll
                for (int j = 0; j < 4; ++j)
                    acc[i][j] = fmaf(aa[i], bb[j], acc[i][j]);
        }
    }
#pragma unroll
    for (int i = 0; i < 4; ++i) {
        float4 o;
        o.x = acc[i][0] + bias[c0 + tx * 4 + 0];
        o.y = acc[i][1] + bias[c0 + tx * 4 + 1];
        o.z = acc[i][2] + bias[c0 + tx * 4 + 2];
        o.w = acc[i][3] + bias[c0 + tx * 4 + 3];
        *(float4*)(out + (size_t)(r0 + ty * 4 + i) * DIM + c0 + tx * 4) = o;
    }
}

// ---------------- row squared norms ----------------
__global__ __launch_bounds__(64) void row_norm(const float* __restrict__ x,
                                               float* __restrict__ out) {
    const int row = blockIdx.x, lane = threadIdx.x;
    float4 v = *(const float4*)(x + (size_t)row * DIM + lane * 4);
    float s = v.x * v.x + v.y * v.y + v.z * v.z + v.w * v.w;
#pragma unroll
    for (int off = 32; off > 0; off >>= 1) s += __shfl_xor(s, off);
    if (lane == 0) out[row] = s;
}

// ---------------- split fp32 -> bf16 hi + bf16 lo (lo = bf16(x - hi)) ----------------
__global__ __launch_bounds__(256) void split_bf16(const float* __restrict__ x,
                                                  ushort_t* __restrict__ hi,
                                                  ushort_t* __restrict__ lo) {
    const int idx = (blockIdx.x * 256 + threadIdx.x) * 4;
    float4 v = *(const float4*)(x + idx);
    ushort_t h0 = f2bf(v.x), h1 = f2bf(v.y), h2 = f2bf(v.z), h3 = f2bf(v.w);
    ushort4 hv = make_ushort4(h0, h1, h2, h3);
    ushort4 lv = make_ushort4(f2bf(v.x - bf2f(h0)), f2bf(v.y - bf2f(h1)),
                              f2bf(v.z - bf2f(h2)), f2bf(v.w - bf2f(h3)));
    *(ushort4*)(hi + idx) = hv;
    *(ushort4*)(lo + idx) = lv;
}

// ---------------- S = SCALE2*(qn_i + kn_j - 2*q_i.k_j) via split-bf16 MFMA ----------
__global__ __launch_bounds__(256) void dist_mfma(const ushort_t* __restrict__ qh,
                                                 const ushort_t* __restrict__ ql,
                                                 const ushort_t* __restrict__ kh,
                                                 const ushort_t* __restrict__ kl,
                                                 const float* __restrict__ qn,
                                                 const float* __restrict__ kn,
                                                 float* __restrict__ S) {
    const int t = threadIdx.x;
    const int wv = t >> 6, lane = t & 63;
    const int r0 = blockIdx.y * 128 + (wv >> 1) * 64;
    const int c0 = blockIdx.x * 128 + (wv & 1) * 64;
    const int fr = lane & 15;       // row (A) / col (B) within 16x16 tile
    const int fq = lane >> 4;       // quad -> k-subrange / C-row group
    facc acc[4][4];
#pragma unroll
    for (int i = 0; i < 4; ++i)
#pragma unroll
        for (int j = 0; j < 4; ++j) acc[i][j] = (facc){0.f, 0.f, 0.f, 0.f};

    for (int k0 = 0; k0 < DIM; k0 += 32) {
        const int ks = k0 + fq * 8;
        bfrag ah[4], al[4], bh[4], bl[4];
#pragma unroll
        for (int mi = 0; mi < 4; ++mi) {
            const size_t ao = (size_t)(r0 + mi * 16 + fr) * DIM + ks;
            ah[mi] = *(const bfrag*)(qh + ao);
            al[mi] = *(const bfrag*)(ql + ao);
        }
#pragma unroll
        for (int ni = 0; ni < 4; ++ni) {
            const size_t bo = (size_t)(c0 + ni * 16 + fr) * DIM + ks;
            bh[ni] = *(const bfrag*)(kh + bo);
            bl[ni] = *(const bfrag*)(kl + bo);
        }
#pragma unroll
        for (int mi = 0; mi < 4; ++mi)
#pragma unroll
            for (int ni = 0; ni < 4; ++ni) {
                acc[mi][ni] = __builtin_amdgcn_mfma_f32_16x16x32_bf16(ah[mi], bh[ni], acc[mi][ni], 0, 0, 0);
                acc[mi][ni] = __builtin_amdgcn_mfma_f32_16x16x32_bf16(ah[mi], bl[ni], acc[mi][ni], 0, 0, 0);
                acc[mi][ni] = __builtin_amdgcn_mfma_f32_16x16x32_bf16(al[mi], bh[ni], acc[mi][ni], 0, 0, 0);
                acc[mi][ni] = __builtin_amdgcn_mfma_f32_16x16x32_bf16(al[mi], bl[ni], acc[mi][ni], 0, 0, 0);
            }
    }
    // epilogue: S[row][col] = (qn + kn - 2*dot) * SCALE2
#pragma unroll
    for (int mi = 0; mi < 4; ++mi) {
        float qnr[4];
#pragma unroll
        for (int r = 0; r < 4; ++r) qnr[r] = qn[r0 + mi * 16 + fq * 4 + r];
#pragma unroll
        for (int ni = 0; ni < 4; ++ni) {
            const int col = c0 + ni * 16 + fr;
            const float knc = kn[col];
#pragma unroll
            for (int r = 0; r < 4; ++r) {
                const int row = r0 + mi * 16 + fq * 4 + r;
                S[(size_t)row * NR + col] = (qnr[r] + knc - 2.0f * acc[mi][ni][r]) * SCALE2;
            }
        }
    }
}

// ---------------- MLP logits: relu(A@W1+b1)@W2 + b2 ----------------
__global__ __launch_bounds__(128) void mlp_logits(const float* __restrict__ A,
                                                  const float* __restrict__ W1,
                                                  const float* __restrict__ b1,
                                                  const float* __restrict__ W2,
                                                  const float* __restrict__ b2,
                                                  float* __restrict__ logits) {
    __shared__ float ar[DIM];
    __shared__ float red[2];
    const int t = threadIdx.x;
    const int row = blockIdx.x;
    *(float2*)&ar[t * 2] = *(const float2*)(A + (size_t)row * DIM + t * 2);
    __syncthreads();
    float h = b1[t];
#pragma unroll 8
    for (int kk = 0; kk < DIM; ++kk) h = fmaf(ar[kk], W1[kk * 128 + t], h);
    float val = fmaxf(h, 0.0f) * W2[t];
#pragma unroll
    for (int off = 32; off > 0; off >>= 1) val += __shfl_xor(val, off);
    if ((t & 63) == 0) red[t >> 6] = val;
    __syncthreads();
    if (t == 0) logits[row] = red[0] + red[1] + b2[0];
}

// ---------------- softmax over 8192 logits -> log2(b + 1e-20) ----------------
__global__ __launch_bounds__(1024) void softmax_logb(const float* __restrict__ logits,
                                                     float* __restrict__ logb2) {
    __shared__ float redm[16], reds[16];
    const int t = threadIdx.x;
    float l[8];
    float m = -INFINITY;
#pragma unroll
    for (int i = 0; i < 8; ++i) { l[i] = logits[i * 1024 + t]; m = fmaxf(m, l[i]); }
#pragma unroll
    for (int off = 32; off > 0; off >>= 1) m = fmaxf(m, __shfl_xor(m, off));
    if ((t & 63) == 0) redm[t >> 6] = m;
    __syncthreads();
    if (t < 64) {
        float v = (t < 16) ? redm[t] : -INFINITY;
#pragma unroll
        for (int off = 8; off > 0; off >>= 1) v = fmaxf(v, __shfl_xor(v, off));
        if (t == 0) redm[0] = v;
    }
    __syncthreads();
    m = redm[0];
    float s = 0.0f;
#pragma unroll
    for (int i = 0; i < 8; ++i) s += __expf(l[i] - m);
#pragma unroll
    for (int off = 32; off > 0; off >>= 1) s += __shfl_xor(s, off);
    if ((t & 63) == 0) reds[t >> 6] = s;
    __syncthreads();
    if (t < 64) {
        float v = (t < 16) ? reds[t] : 0.0f;
#pragma unroll
        for (int off = 8; off > 0; off >>= 1) v += __shfl_xor(v, off);
        if (t == 0) reds[0] = v;
    }
    __syncthreads();
    s = reds[0];
    float invs = 1.0f / s;
#pragma unroll
    for (int i = 0; i < 8; ++i)
        logb2[i * 1024 + t] = log2f(__expf(l[i] - m) * invs + 1e-20f);
}

// ---------------- fused iteration: wave-aligned, register-direct, LDS-free S -------
// R2/R3 lesson (rule #20, twice): ANY addressable formulation of the ping-pong
// buffers (runtime-selected pointer OR array-by-reference into a lambda) pins
// them in scratch -> 0.5 GB spill traffic. This version uses 16 NAMED float4
// variables and a macro-stamped body: pure SSA, scratch impossible.
// Structure: each wave owns a 1024-col segment for all 16 rows; thread t owns
// cols {wv*1024 + lane*4 + it*256}. Sub-chunk = 2 rows -> 8 global_load_dwordx4
// into named regs, issued one sub-chunk ahead; loads stay in flight across the
// raw (lgkm-only, non-draining) barrier. ONE barrier per sub-chunk; redm/reds
// double-buffered by sc&1 (race-free: next write of same buffer is separated
// by the sc+1 barrier — verified passing in R2/R3).
#define SUBCHUNK(sc, pb, C0,C1,C2,C3,C4,C5,C6,C7, N0,N1,N2,N3,N4,N5,N6,N7) { \
    if ((sc) + 1 < NSUB) { \
        const float* Sn0 = Sb + (size_t)(2 * (sc) + 2) * NR; \
        const float* Sn1 = Sb + (size_t)(2 * (sc) + 3) * NR; \
        N0 = *(const float4*)(Sn0 +   0); N1 = *(const float4*)(Sn0 + 256); \
        N2 = *(const float4*)(Sn0 + 512); N3 = *(const float4*)(Sn0 + 768); \
        N4 = *(const float4*)(Sn1 +   0); N5 = *(const float4*)(Sn1 + 256); \
        N6 = *(const float4*)(Sn1 + 512); N7 = *(const float4*)(Sn1 + 768); \
    } \
    float m0_ = -INFINITY, s0_ = 0.0f, m1_ = -INFINITY, s1_ = 0.0f; \
    { \
        float4 gv0 = *(const float4*)&gsh[col0 +   0]; \
        lse_upd4(m0_, s0_, C0.x + gv0.x, C0.y + gv0.y, C0.z + gv0.z, C0.w + gv0.w); \
        lse_upd4(m1_, s1_, C4.x + gv0.x, C4.y + gv0.y, C4.z + gv0.z, C4.w + gv0.w); \
        float4 gv1 = *(const float4*)&gsh[col0 + 256]; \
        lse_upd4(m0_, s0_, C1.x + gv1.x, C1.y + gv1.y, C1.z + gv1.z, C1.w + gv1.w); \
        lse_upd4(m1_, s1_, C5.x + gv1.x, C5.y + gv1.y, C5.z + gv1.z, C5.w + gv1.w); \
        float4 gv2 = *(const float4*)&gsh[col0 + 512]; \
        lse_upd4(m0_, s0_, C2.x + gv2.x, C2.y + gv2.y, C2.z + gv2.z, C2.w + gv2.w); \
        lse_upd4(m1_, s1_, C6.x + gv2.x, C6.y + gv2.y, C6.z + gv2.z, C6.w + gv2.w); \
        float4 gv3 = *(const float4*)&gsh[col0 + 768]; \
        lse_upd4(m0_, s0_, C3.x + gv3.x, C3.y + gv3.y, C3.z + gv3.z, C3.w + gv3.w); \
        lse_upd4(m1_, s1_, C7.x + gv3.x, C7.y + gv3.y, C7.z + gv3.z, C7.w + gv3.w); \
    } \
    _Pragma("unroll") \
    for (int off_ = 32; off_ > 0; off_ >>= 1) { \
        float am_ = __shfl_xor(m0_, off_), as_ = __shfl_xor(s0_, off_); \
        lse_comb2(m0_, s0_, am_, as_); \
        float bm_ = __shfl_xor(m1_, off_), bs_ = __shfl_xor(s1_, off_); \
        lse_comb2(m1_, s1_, bm_, bs_); \
    } \
    if (lane == 0) { \
        redm[pb][0][wv] = m0_; reds[pb][0][wv] = s0_; \
        redm[pb][1][wv] = m1_; reds[pb][1][wv] = s1_; \
    } \
    asm volatile("s_waitcnt lgkmcnt(0)" ::: "memory"); \
    __builtin_amdgcn_s_barrier(); \
    float M0_ = redm[pb][0][0], P0_ = reds[pb][0][0]; \
    lse_comb2(M0_, P0_, redm[pb][0][1], reds[pb][0][1]); \
    float M1_ = redm[pb][0][2], P1_ = reds[pb][0][2]; \
    lse_comb2(M1_, P1_, redm[pb][0][3], reds[pb][0][3]); \
    float M2_ = redm[pb][0][4], P2_ = reds[pb][0][4]; \
    lse_comb2(M2_, P2_, redm[pb][0][5], reds[pb][0][5]); \
    float M3_ = redm[pb][0][6], P3_ = reds[pb][0][6]; \
    lse_comb2(M3_, P3_, redm[pb][0][7], reds[pb][0][7]); \
    lse_comb2(M0_, P0_, M1_, P1_); \
    lse_comb2(M2_, P2_, M3_, P3_); \
    lse_comb2(M0_, P0_, M2_, P2_); \
    float Q0_ = redm[pb][1][0], R0_ = reds[pb][1][0]; \
    lse_comb2(Q0_, R0_, redm[pb][1][1], reds[pb][1][1]); \
    float Q1_ = redm[pb][1][2], R1_ = reds[pb][1][2]; \
    lse_comb2(Q1_, R1_, redm[pb][1][3], reds[pb][1][3]); \
    float Q2_ = redm[pb][1][4], R2_ = reds[pb][1][4]; \
    lse_comb2(Q2_, R2_, redm[pb][1][5], reds[pb][1][5]); \
    float Q3_ = redm[pb][1][6], R3_ = reds[pb][1][6]; \
    lse_comb2(Q3_, R3_, redm[pb][1][7], reds[pb][1][7]); \
    lse_comb2(Q0_, R0_, Q1_, R1_); \
    lse_comb2(Q2_, R2_, Q3_, R3_); \
    lse_comb2(Q0_, R0_, Q2_, R2_); \
    const float fr0_ = lbsh[2 * (sc) + 0] - (M0_ + flog2(P0_)); \
    const float fr1_ = lbsh[2 * (sc) + 1] - (Q0_ + flog2(R0_)); \
    if (t == 2 * (sc))     fmine = fr0_; \
    if (t == 2 * (sc) + 1) fmine = fr1_; \
    lse_upd2(cm[0][0], cs[0][0], C0.x + fr0_, C4.x + fr1_); \
    lse_upd2(cm[0][1], cs[0][1], C0.y + fr0_, C4.y + fr1_); \
    lse_upd2(cm[0][2], cs[0][2], C0.z + fr0_, C4.z + fr1_); \
    lse_upd2(cm[0][3], cs[0][3], C0.w + fr0_, C4.w + fr1_); \
    lse_upd2(cm[1][0], cs[1][0], C1.x + fr0_, C5.x + fr1_); \
    lse_upd2(cm[1][1], cs[1][1], C1.y + fr0_, C5.y + fr1_); \
    lse_upd2(cm[1][2], cs[1][2], C1.z + fr0_, C5.z + fr1_); \
    lse_upd2(cm[1][3], cs[1][3], C1.w + fr0_, C5.w + fr1_); \
    lse_upd2(cm[2][0], cs[2][0], C2.x + fr0_, C6.x + fr1_); \
    lse_upd2(cm[2][1], cs[2][1], C2.y + fr0_, C6.y + fr1_); \
    lse_upd2(cm[2][2], cs[2][2], C2.z + fr0_, C6.z + fr1_); \
    lse_upd2(cm[2][3], cs[2][3], C2.w + fr0_, C6.w + fr1_); \
    lse_upd2(cm[3][0], cs[3][0], C3.x + fr0_, C7.x + fr1_); \
    lse_upd2(cm[3][1], cs[3][1], C3.y + fr0_, C7.y + fr1_); \
    lse_upd2(cm[3][2], cs[3][2], C3.z + fr0_, C7.z + fr1_); \
    lse_upd2(cm[3][3], cs[3][3], C3.w + fr0_, C7.w + fr1_); \
}

__global__ __launch_bounds__(512, 4) void iter_fused(const float* __restrict__ S,
                                                     const float* __restrict__ g,
                                                     const float* __restrict__ logb2,
                                                     float* __restrict__ f,
                                                     float* __restrict__ pm) {
    __shared__ float gsh[NR];                        // 32 KB, staged once
    __shared__ float redm[2][2][8], reds[2][2][8];   // [sc&1][row-in-pair][wave]
    __shared__ float lbsh[CROWS];
    const int t = threadIdx.x;
    const int wv = t >> 6, lane = t & 63;
    const int chunk = blockIdx.x;
    const int r0 = chunk * CROWS;
    const int col0 = wv * 1024 + lane * 4;   // thread's base col (cols col0+it*256)

    if (t < CROWS) lbsh[t] = logb2[r0 + t];
    // stage g into LDS: 512 threads x 4 float4, coalesced
#pragma unroll
    for (int it = 0; it < 4; ++it) {
        float4 gv = *(const float4*)(g + t * 4 + it * 2048);
        *(float4*)&gsh[t * 4 + it * 2048] = gv;
    }

    // column accumulators for the thread's 16 owned columns (constant-indexed)
    float cm[4][4], cs[4][4];
#pragma unroll
    for (int it = 0; it < 4; ++it)
#pragma unroll
        for (int c = 0; c < 4; ++c) { cm[it][c] = -INFINITY; cs[it][c] = 0.0f; }

    const float* Sb = S + (size_t)r0 * NR + col0;
    float fmine = 0.0f;

    __syncthreads();   // gsh/lbsh ready (full drain OK: prologue only)

    // ping-pong state: 16 NAMED float4 (pure SSA — cannot hit scratch)
    float4 a0, a1, a2, a3, a4, a5, a6, a7;
    float4 b0, b1, b2, b3, b4, b5, b6, b7;
    {   // prologue: rows 0,1 into a*
        const float* S0 = Sb;
        const float* S1 = Sb + (size_t)NR;
        a0 = *(const float4*)(S0 +   0); a1 = *(const float4*)(S0 + 256);
        a2 = *(const float4*)(S0 + 512); a3 = *(const float4*)(S0 + 768);
        a4 = *(const float4*)(S1 +   0); a5 = *(const float4*)(S1 + 256);
        a6 = *(const float4*)(S1 + 512); a7 = *(const float4*)(S1 + 768);
    }

    SUBCHUNK(0, 0, a0,a1,a2,a3,a4,a5,a6,a7, b0,b1,b2,b3,b4,b5,b6,b7)
    SUBCHUNK(1, 1, b0,b1,b2,b3,b4,b5,b6,b7, a0,a1,a2,a3,a4,a5,a6,a7)
    SUBCHUNK(2, 0, a0,a1,a2,a3,a4,a5,a6,a7, b0,b1,b2,b3,b4,b5,b6,b7)
    SUBCHUNK(3, 1, b0,b1,b2,b3,b4,b5,b6,b7, a0,a1,a2,a3,a4,a5,a6,a7)
    SUBCHUNK(4, 0, a0,a1,a2,a3,a4,a5,a6,a7, b0,b1,b2,b3,b4,b5,b6,b7)
    SUBCHUNK(5, 1, b0,b1,b2,b3,b4,b5,b6,b7, a0,a1,a2,a3,a4,a5,a6,a7)
    SUBCHUNK(6, 0, a0,a1,a2,a3,a4,a5,a6,a7, b0,b1,b2,b3,b4,b5,b6,b7)
    SUBCHUNK(7, 1, b0,b1,b2,b3,b4,b5,b6,b7, a0,a1,a2,a3,a4,a5,a6,a7)

    if (t < CROWS) f[r0 + t] = fmine;

    // write column partials for this chunk as a single float L = m + log2(s)
#pragma unroll
    for (int it = 0; it < 4; ++it) {
        float4 L;
        L.x = cm[it][0] + flog2(cs[it][0]);
        L.y = cm[it][1] + flog2(cs[it][1]);
        L.z = cm[it][2] + flog2(cs[it][2]);
        L.w = cm[it][3] + flog2(cs[it][3]);
        *(float4*)&pm[(size_t)chunk * NR + col0 + it * 256] = L;
    }
}

// ---------------- combine partials -> g (256 blocks, two-level LSE) ----------------
__global__ __launch_bounds__(256) void col_combine(const float* __restrict__ pm,
                                                   float* __restrict__ g,
                                                   float log_a2) {
    __shared__ float Lsh[8][32];
    const int cl = threadIdx.x & 31;       // column within block
    const int gp = threadIdx.x >> 5;       // chunk group (0..7), 64 chunks each
    const int col = blockIdx.x * 32 + cl;
    float m = -INFINITY, s = 0.0f;
#pragma unroll
    for (int ch = gp * 64; ch < gp * 64 + 64; ch += 4) {
        float l0 = pm[(size_t)(ch + 0) * NR + col];
        float l1 = pm[(size_t)(ch + 1) * NR + col];
        float l2 = pm[(size_t)(ch + 2) * NR + col];
        float l3 = pm[(size_t)(ch + 3) * NR + col];
        lse_upd4(m, s, l0, l1, l2, l3);
    }
    Lsh[gp][cl] = m + flog2(s);
    __syncthreads();
    if (gp == 0) {
        float mm = -INFINITY, ss = 0.0f;
        lse_upd4(mm, ss, Lsh[0][cl], Lsh[1][cl], Lsh[2][cl], Lsh[3][cl]);
        lse_upd4(mm, ss, Lsh[4][cl], Lsh[5][cl], Lsh[6][cl], Lsh[7][cl]);
        g[col] = log_a2 - (mm + flog2(ss));
    }
}

// ---------------- T = exp2(f + S + g), in place; global sum == 1 analytically ------
// note: no __restrict__ on S/out — they alias (in-place)
__global__ __launch_bounds__(256) void write_pass(const float* S,
                                                  const float* __restrict__ f,
                                                  const float* __restrict__ g,
                                                  float* out) {
    const int wv = threadIdx.x >> 6, lane = threadIdx.x & 63;
    const int row = blockIdx.x * 4 + wv;
    const float fi = f[row];
    const float4* Sr = (const float4*)(S + (size_t)row * NR);
    const float4* gr = (const float4*)g;
    float4* Or = (float4*)(out + (size_t)row * NR);
#pragma unroll 4
    for (int it = 0; it < NR / 256; ++it) {
        const int idx = it * 64 + lane;
        float4 sv = Sr[idx];
        float4 gv = gr[idx];
        float4 o;
        o.x = fexp2(fi + sv.x + gv.x);
        o.y = fexp2(fi + sv.y + gv.y);
        o.z = fexp2(fi + sv.z + gv.z);
        o.w = fexp2(fi + sv.w + gv.w);
        Or[idx] = o;
    }
}

extern "C" void kernel_launch(void* const* d_in, const int* in_sizes, int n_in,
                              void* d_out, int out_size, void* d_ws, size_t ws_size,
                              hipStream_t stream) {
    (void)in_sizes; (void)n_in; (void)out_size; (void)ws_size;
    const float* A  = (const float*)d_in[0];
    const float* Tk = (const float*)d_in[1];
    const float* Wq = (const float*)d_in[2];
    const float* bq = (const float*)d_in[3];
    const float* Wk = (const float*)d_in[4];
    const float* bk = (const float*)d_in[5];
    const float* W1 = (const float*)d_in[6];
    const float* b1 = (const float*)d_in[7];
    const float* W2 = (const float*)d_in[8];
    const float* b2 = (const float*)d_in[9];
    float* S  = (float*)d_out;           // 8192x8192 base-2 log_K lives in d_out
    float* ws = (float*)d_ws;
    float* qn     = ws; ws += NR;
    float* kn     = ws; ws += NR;
    float* logb2  = ws; ws += NR;
    float* logits = ws; ws += NR;
    float* f      = ws; ws += NR;
    float* g      = ws; ws += NR;
    float* pm     = ws; ws += (size_t)NBLK * NR;   // 16 MB
    float* q      = ws; ws += (size_t)NR * DIM;    // 8 MB
    float* k      = ws; ws += (size_t)NR * DIM;    // 8 MB
    // bf16 split arrays overlay pm (16.78 MB == 4 x NR*DIM ushorts): they are
    // dead once dist_mfma finishes, before the first iter_fused writes pm.
    ushort_t* qh = (ushort_t*)pm;
    ushort_t* ql = qh + (size_t)NR * DIM;
    ushort_t* kh = ql + (size_t)NR * DIM;
    ushort_t* kl = kh + (size_t)NR * DIM;

    const float log_a2 = -13.0f; // log2(1/8192 + 1e-20)

    init_zero<<<32, 256, 0, stream>>>(g);
    gemm_qk<<<dim3(128, 4), 256, 0, stream>>>(A, Wq, bq, q);
    gemm_qk<<<dim3(128, 4), 256, 0, stream>>>(Tk, Wk, bk, k);
    row_norm<<<NR, 64, 0, stream>>>(q, qn);
    row_norm<<<NR, 64, 0, stream>>>(k, kn);
    split_bf16<<<NR * DIM / 1024, 256, 0, stream>>>(q, qh, ql);
    split_bf16<<<NR * DIM / 1024, 256, 0, stream>>>(k, kh, kl);
    mlp_logits<<<NR, 128, 0, stream>>>(A, W1, b1, W2, b2, logits);
    softmax_logb<<<1, 1024, 0, stream>>>(logits, logb2);
    dist_mfma<<<dim3(64, 64), 256, 0, stream>>>(qh, ql, kh, kl, qn, kn, S);
    for (int it = 0; it < 50; ++it) {
        iter_fused<<<NBLK, 512, 0, stream>>>(S, g, logb2, f, pm);
        col_combine<<<NR / 32, 256, 0, stream>>>(pm, g, log_a2);
    }
    write_pass<<<NR / 4, 256, 0, stream>>>(S, f, g, S);
}

// Round 5
// 9781.557 us; speedup vs baseline: 1.4893x; 1.3986x over previous
//
#include <hip/hip_runtime.h>
#include <math.h>

#define NR 8192      // NA == NT
#define DIM 256
#define NBLK 512     // fused-kernel blocks == column-partial chunks (2 per CU)
#define CROWS 16     // rows per chunk
#define NSUB 8       // sub-chunks per chunk (2 rows each, reg ping-pong)
// 10 * log2(e): converts distances directly into base-2 log domain
#define SCALE2 14.426950408889634f

typedef unsigned short ushort_t;
typedef __attribute__((ext_vector_type(8))) short bfrag;   // 8 bf16 (4 VGPRs)
typedef __attribute__((ext_vector_type(4))) float facc;    // 4 fp32 acc

// v_exp_f32 / v_log_f32 are base-2 natively — use them raw
__device__ __forceinline__ float fexp2(float x) {
#if __has_builtin(__builtin_amdgcn_exp2f)
    return __builtin_amdgcn_exp2f(x);
#else
    return exp2f(x);
#endif
}
__device__ __forceinline__ float flog2(float x) {
#if __has_builtin(__builtin_amdgcn_logf)
    return __builtin_amdgcn_logf(x);
#else
    return log2f(x);
#endif
}

// base-2 online LSE combine
__device__ __forceinline__ void lse_comb2(float& m, float& s, float mo, float so) {
    float nm = fmaxf(m, mo);
    s = s * fexp2(m - nm) + so * fexp2(mo - nm);
    m = nm;
}

// grouped-4 online LSE update (1 tree-max + 1 correction exp per 4 values)
__device__ __forceinline__ void lse_upd4(float& m, float& s,
                                         float v0, float v1, float v2, float v3) {
    float m4 = fmaxf(fmaxf(v0, v1), fmaxf(v2, v3));
    float nm = fmaxf(m, m4);
    float e = fexp2(v0 - nm) + fexp2(v1 - nm) + fexp2(v2 - nm) + fexp2(v3 - nm);
    s = fmaf(s, fexp2(m - nm), e);
    m = nm;
}

// grouped-2 online LSE update
__device__ __forceinline__ void lse_upd2(float& m, float& s, float v0, float v1) {
    float m2 = fmaxf(v0, v1);
    float nm = fmaxf(m, m2);
    float e = fexp2(v0 - nm) + fexp2(v1 - nm);
    s = fmaf(s, fexp2(m - nm), e);
    m = nm;
}

// RNE float -> bf16 bits (manual: deterministic, no API variance)
__device__ __forceinline__ ushort_t f2bf(float x) {
    unsigned u = __float_as_uint(x);
    u += 0x7FFFu + ((u >> 16) & 1u);
    return (ushort_t)(u >> 16);
}
__device__ __forceinline__ float bf2f(ushort_t b) {
    return __uint_as_float(((unsigned)b) << 16);
}

// ---------------- init ----------------
__global__ void init_zero(float* __restrict__ g) {
    int t = blockIdx.x * 256 + threadIdx.x;
    if (t < NR) g[t] = 0.0f;
}

// ---------------- out[M,DIM] = A[M,DIM] @ W[DIM,DIM] + bias ----------------
__global__ __launch_bounds__(256) void gemm_qk(const float* __restrict__ A,
                                               const float* __restrict__ W,
                                               const float* __restrict__ bias,
                                               float* __restrict__ out) {
    __shared__ float As[16][68];
    __shared__ float Ws[16][68];
    const int t  = threadIdx.x;
    const int r0 = blockIdx.x * 64;
    const int c0 = blockIdx.y * 64;
    const int ty = t >> 4, tx = t & 15;
    const int arow = t >> 2;
    const int ak   = (t & 3) * 4;
    const int wrow = t >> 4;
    const int wcol = (t & 15) * 4;
    float acc[4][4] = {};
    for (int k0 = 0; k0 < DIM; k0 += 16) {
        float4 av = *(const float4*)(A + (size_t)(r0 + arow) * DIM + k0 + ak);
        float4 wv = *(const float4*)(W + (size_t)(k0 + wrow) * DIM + c0 + wcol);
        __syncthreads();
        As[ak + 0][arow] = av.x; As[ak + 1][arow] = av.y;
        As[ak + 2][arow] = av.z; As[ak + 3][arow] = av.w;
        *(float4*)&Ws[wrow][wcol] = wv;
        __syncthreads();
#pragma unroll
        for (int kk = 0; kk < 16; ++kk) {
            float4 a = *(const float4*)&As[kk][ty * 4];
            float4 b = *(const float4*)&Ws[kk][tx * 4];
            float aa[4] = {a.x, a.y, a.z, a.w};
            float bb[4] = {b.x, b.y, b.z, b.w};
#pragma unroll
            for (int i = 0; i < 4; ++i)
#pragma unroll
                for (int j = 0; j < 4; ++j)
                    acc[i][j] = fmaf(aa[i], bb[j], acc[i][j]);
        }
    }
#pragma unroll
    for (int i = 0; i < 4; ++i) {
        float4 o;
        o.x = acc[i][0] + bias[c0 + tx * 4 + 0];
        o.y = acc[i][1] + bias[c0 + tx * 4 + 1];
        o.z = acc[i][2] + bias[c0 + tx * 4 + 2];
        o.w = acc[i][3] + bias[c0 + tx * 4 + 3];
        *(float4*)(out + (size_t)(r0 + ty * 4 + i) * DIM + c0 + tx * 4) = o;
    }
}

// ---------------- row squared norms ----------------
__global__ __launch_bounds__(64) void row_norm(const float* __restrict__ x,
                                               float* __restrict__ out) {
    const int row = blockIdx.x, lane = threadIdx.x;
    float4 v = *(const float4*)(x + (size_t)row * DIM + lane * 4);
    float s = v.x * v.x + v.y * v.y + v.z * v.z + v.w * v.w;
#pragma unroll
    for (int off = 32; off > 0; off >>= 1) s += __shfl_xor(s, off);
    if (lane == 0) out[row] = s;
}

// ---------------- split fp32 -> bf16 hi + bf16 lo (lo = bf16(x - hi)) ----------------
__global__ __launch_bounds__(256) void split_bf16(const float* __restrict__ x,
                                                  ushort_t* __restrict__ hi,
                                                  ushort_t* __restrict__ lo) {
    const int idx = (blockIdx.x * 256 + threadIdx.x) * 4;
    float4 v = *(const float4*)(x + idx);
    ushort_t h0 = f2bf(v.x), h1 = f2bf(v.y), h2 = f2bf(v.z), h3 = f2bf(v.w);
    ushort4 hv = make_ushort4(h0, h1, h2, h3);
    ushort4 lv = make_ushort4(f2bf(v.x - bf2f(h0)), f2bf(v.y - bf2f(h1)),
                              f2bf(v.z - bf2f(h2)), f2bf(v.w - bf2f(h3)));
    *(ushort4*)(hi + idx) = hv;
    *(ushort4*)(lo + idx) = lv;
}

// ---------------- S = SCALE2*(qn_i + kn_j - 2*q_i.k_j) via split-bf16 MFMA ----------
__global__ __launch_bounds__(256) void dist_mfma(const ushort_t* __restrict__ qh,
                                                 const ushort_t* __restrict__ ql,
                                                 const ushort_t* __restrict__ kh,
                                                 const ushort_t* __restrict__ kl,
                                                 const float* __restrict__ qn,
                                                 const float* __restrict__ kn,
                                                 float* __restrict__ S) {
    const int t = threadIdx.x;
    const int wv = t >> 6, lane = t & 63;
    const int r0 = blockIdx.y * 128 + (wv >> 1) * 64;
    const int c0 = blockIdx.x * 128 + (wv & 1) * 64;
    const int fr = lane & 15;       // row (A) / col (B) within 16x16 tile
    const int fq = lane >> 4;       // quad -> k-subrange / C-row group
    facc acc[4][4];
#pragma unroll
    for (int i = 0; i < 4; ++i)
#pragma unroll
        for (int j = 0; j < 4; ++j) acc[i][j] = (facc){0.f, 0.f, 0.f, 0.f};

    for (int k0 = 0; k0 < DIM; k0 += 32) {
        const int ks = k0 + fq * 8;
        bfrag ah[4], al[4], bh[4], bl[4];
#pragma unroll
        for (int mi = 0; mi < 4; ++mi) {
            const size_t ao = (size_t)(r0 + mi * 16 + fr) * DIM + ks;
            ah[mi] = *(const bfrag*)(qh + ao);
            al[mi] = *(const bfrag*)(ql + ao);
        }
#pragma unroll
        for (int ni = 0; ni < 4; ++ni) {
            const size_t bo = (size_t)(c0 + ni * 16 + fr) * DIM + ks;
            bh[ni] = *(const bfrag*)(kh + bo);
            bl[ni] = *(const bfrag*)(kl + bo);
        }
#pragma unroll
        for (int mi = 0; mi < 4; ++mi)
#pragma unroll
            for (int ni = 0; ni < 4; ++ni) {
                acc[mi][ni] = __builtin_amdgcn_mfma_f32_16x16x32_bf16(ah[mi], bh[ni], acc[mi][ni], 0, 0, 0);
                acc[mi][ni] = __builtin_amdgcn_mfma_f32_16x16x32_bf16(ah[mi], bl[ni], acc[mi][ni], 0, 0, 0);
                acc[mi][ni] = __builtin_amdgcn_mfma_f32_16x16x32_bf16(al[mi], bh[ni], acc[mi][ni], 0, 0, 0);
                acc[mi][ni] = __builtin_amdgcn_mfma_f32_16x16x32_bf16(al[mi], bl[ni], acc[mi][ni], 0, 0, 0);
            }
    }
    // epilogue: S[row][col] = (qn + kn - 2*dot) * SCALE2
#pragma unroll
    for (int mi = 0; mi < 4; ++mi) {
        float qnr[4];
#pragma unroll
        for (int r = 0; r < 4; ++r) qnr[r] = qn[r0 + mi * 16 + fq * 4 + r];
#pragma unroll
        for (int ni = 0; ni < 4; ++ni) {
            const int col = c0 + ni * 16 + fr;
            const float knc = kn[col];
#pragma unroll
            for (int r = 0; r < 4; ++r) {
                const int row = r0 + mi * 16 + fq * 4 + r;
                S[(size_t)row * NR + col] = (qnr[r] + knc - 2.0f * acc[mi][ni][r]) * SCALE2;
            }
        }
    }
}

// ---------------- MLP logits: relu(A@W1+b1)@W2 + b2 ----------------
__global__ __launch_bounds__(128) void mlp_logits(const float* __restrict__ A,
                                                  const float* __restrict__ W1,
                                                  const float* __restrict__ b1,
                                                  const float* __restrict__ W2,
                                                  const float* __restrict__ b2,
                                                  float* __restrict__ logits) {
    __shared__ float ar[DIM];
    __shared__ float red[2];
    const int t = threadIdx.x;
    const int row = blockIdx.x;
    *(float2*)&ar[t * 2] = *(const float2*)(A + (size_t)row * DIM + t * 2);
    __syncthreads();
    float h = b1[t];
#pragma unroll 8
    for (int kk = 0; kk < DIM; ++kk) h = fmaf(ar[kk], W1[kk * 128 + t], h);
    float val = fmaxf(h, 0.0f) * W2[t];
#pragma unroll
    for (int off = 32; off > 0; off >>= 1) val += __shfl_xor(val, off);
    if ((t & 63) == 0) red[t >> 6] = val;
    __syncthreads();
    if (t == 0) logits[row] = red[0] + red[1] + b2[0];
}

// ---------------- softmax over 8192 logits -> log2(b + 1e-20) ----------------
__global__ __launch_bounds__(1024) void softmax_logb(const float* __restrict__ logits,
                                                     float* __restrict__ logb2) {
    __shared__ float redm[16], reds[16];
    const int t = threadIdx.x;
    float l[8];
    float m = -INFINITY;
#pragma unroll
    for (int i = 0; i < 8; ++i) { l[i] = logits[i * 1024 + t]; m = fmaxf(m, l[i]); }
#pragma unroll
    for (int off = 32; off > 0; off >>= 1) m = fmaxf(m, __shfl_xor(m, off));
    if ((t & 63) == 0) redm[t >> 6] = m;
    __syncthreads();
    if (t < 64) {
        float v = (t < 16) ? redm[t] : -INFINITY;
#pragma unroll
        for (int off = 8; off > 0; off >>= 1) v = fmaxf(v, __shfl_xor(v, off));
        if (t == 0) redm[0] = v;
    }
    __syncthreads();
    m = redm[0];
    float s = 0.0f;
#pragma unroll
    for (int i = 0; i < 8; ++i) s += __expf(l[i] - m);
#pragma unroll
    for (int off = 32; off > 0; off >>= 1) s += __shfl_xor(s, off);
    if ((t & 63) == 0) reds[t >> 6] = s;
    __syncthreads();
    if (t < 64) {
        float v = (t < 16) ? reds[t] : 0.0f;
#pragma unroll
        for (int off = 8; off > 0; off >>= 1) v += __shfl_xor(v, off);
        if (t == 0) reds[0] = v;
    }
    __syncthreads();
    s = reds[0];
    float invs = 1.0f / s;
#pragma unroll
    for (int i = 0; i < 8; ++i)
        logb2[i * 1024 + t] = log2f(__expf(l[i] - m) * invs + 1e-20f);
}

// ---------------- fused iteration: wave-aligned, register-direct, LDS-free S -------
// R2-R4 lesson: the 0.5 GB "spill" traffic was the register ALLOCATOR spilling
// to meet a 64-VGPR budget imposed by __launch_bounds__(512, 4) (empirically:
// CUDA-style semantics, 4 BLOCKS/CU = 8 waves/EU = 512/8 = 64 VGPRs; the
// VGPR_Count=64 in every spilling round is the fingerprint). This structure
// needs ~110 live VGPRs (16 named float4 ping-pong + cm/cs + temps), so use
// (512, 2): 2 blocks/CU -> 128-VGPR cap. Occupancy unchanged (grid is 512
// blocks on 256 CUs = 2 blocks/CU anyway; LDS 33 KB x 2 = 66 KB < 160 KB).
// Body: macro-stamped pure-SSA named scalars (rule #20 — no addressable
// arrays); one raw lgkm-only barrier per sub-chunk; prefetch loads for sc+1
// issued before compute on sc and left IN FLIGHT across the barrier.
#define SUBCHUNK(sc, pb, C0,C1,C2,C3,C4,C5,C6,C7, N0,N1,N2,N3,N4,N5,N6,N7) { \
    if ((sc) + 1 < NSUB) { \
        const float* Sn0 = Sb + (size_t)(2 * (sc) + 2) * NR; \
        const float* Sn1 = Sb + (size_t)(2 * (sc) + 3) * NR; \
        N0 = *(const float4*)(Sn0 +   0); N1 = *(const float4*)(Sn0 + 256); \
        N2 = *(const float4*)(Sn0 + 512); N3 = *(const float4*)(Sn0 + 768); \
        N4 = *(const float4*)(Sn1 +   0); N5 = *(const float4*)(Sn1 + 256); \
        N6 = *(const float4*)(Sn1 + 512); N7 = *(const float4*)(Sn1 + 768); \
    } \
    float m0_ = -INFINITY, s0_ = 0.0f, m1_ = -INFINITY, s1_ = 0.0f; \
    { \
        float4 gv0 = *(const float4*)&gsh[col0 +   0]; \
        lse_upd4(m0_, s0_, C0.x + gv0.x, C0.y + gv0.y, C0.z + gv0.z, C0.w + gv0.w); \
        lse_upd4(m1_, s1_, C4.x + gv0.x, C4.y + gv0.y, C4.z + gv0.z, C4.w + gv0.w); \
        float4 gv1 = *(const float4*)&gsh[col0 + 256]; \
        lse_upd4(m0_, s0_, C1.x + gv1.x, C1.y + gv1.y, C1.z + gv1.z, C1.w + gv1.w); \
        lse_upd4(m1_, s1_, C5.x + gv1.x, C5.y + gv1.y, C5.z + gv1.z, C5.w + gv1.w); \
        float4 gv2 = *(const float4*)&gsh[col0 + 512]; \
        lse_upd4(m0_, s0_, C2.x + gv2.x, C2.y + gv2.y, C2.z + gv2.z, C2.w + gv2.w); \
        lse_upd4(m1_, s1_, C6.x + gv2.x, C6.y + gv2.y, C6.z + gv2.z, C6.w + gv2.w); \
        float4 gv3 = *(const float4*)&gsh[col0 + 768]; \
        lse_upd4(m0_, s0_, C3.x + gv3.x, C3.y + gv3.y, C3.z + gv3.z, C3.w + gv3.w); \
        lse_upd4(m1_, s1_, C7.x + gv3.x, C7.y + gv3.y, C7.z + gv3.z, C7.w + gv3.w); \
    } \
    _Pragma("unroll") \
    for (int off_ = 32; off_ > 0; off_ >>= 1) { \
        float am_ = __shfl_xor(m0_, off_), as_ = __shfl_xor(s0_, off_); \
        lse_comb2(m0_, s0_, am_, as_); \
        float bm_ = __shfl_xor(m1_, off_), bs_ = __shfl_xor(s1_, off_); \
        lse_comb2(m1_, s1_, bm_, bs_); \
    } \
    if (lane == 0) { \
        redm[pb][0][wv] = m0_; reds[pb][0][wv] = s0_; \
        redm[pb][1][wv] = m1_; reds[pb][1][wv] = s1_; \
    } \
    asm volatile("s_waitcnt lgkmcnt(0)" ::: "memory"); \
    __builtin_amdgcn_s_barrier(); \
    float M0_ = redm[pb][0][0], P0_ = reds[pb][0][0]; \
    lse_comb2(M0_, P0_, redm[pb][0][1], reds[pb][0][1]); \
    float M1_ = redm[pb][0][2], P1_ = reds[pb][0][2]; \
    lse_comb2(M1_, P1_, redm[pb][0][3], reds[pb][0][3]); \
    float M2_ = redm[pb][0][4], P2_ = reds[pb][0][4]; \
    lse_comb2(M2_, P2_, redm[pb][0][5], reds[pb][0][5]); \
    float M3_ = redm[pb][0][6], P3_ = reds[pb][0][6]; \
    lse_comb2(M3_, P3_, redm[pb][0][7], reds[pb][0][7]); \
    lse_comb2(M0_, P0_, M1_, P1_); \
    lse_comb2(M2_, P2_, M3_, P3_); \
    lse_comb2(M0_, P0_, M2_, P2_); \
    float Q0_ = redm[pb][1][0], R0_ = reds[pb][1][0]; \
    lse_comb2(Q0_, R0_, redm[pb][1][1], reds[pb][1][1]); \
    float Q1_ = redm[pb][1][2], R1_ = reds[pb][1][2]; \
    lse_comb2(Q1_, R1_, redm[pb][1][3], reds[pb][1][3]); \
    float Q2_ = redm[pb][1][4], R2_ = reds[pb][1][4]; \
    lse_comb2(Q2_, R2_, redm[pb][1][5], reds[pb][1][5]); \
    float Q3_ = redm[pb][1][6], R3_ = reds[pb][1][6]; \
    lse_comb2(Q3_, R3_, redm[pb][1][7], reds[pb][1][7]); \
    lse_comb2(Q0_, R0_, Q1_, R1_); \
    lse_comb2(Q2_, R2_, Q3_, R3_); \
    lse_comb2(Q0_, R0_, Q2_, R2_); \
    const float fr0_ = lbsh[2 * (sc) + 0] - (M0_ + flog2(P0_)); \
    const float fr1_ = lbsh[2 * (sc) + 1] - (Q0_ + flog2(R0_)); \
    if (t == 2 * (sc))     fmine = fr0_; \
    if (t == 2 * (sc) + 1) fmine = fr1_; \
    lse_upd2(cm[0][0], cs[0][0], C0.x + fr0_, C4.x + fr1_); \
    lse_upd2(cm[0][1], cs[0][1], C0.y + fr0_, C4.y + fr1_); \
    lse_upd2(cm[0][2], cs[0][2], C0.z + fr0_, C4.z + fr1_); \
    lse_upd2(cm[0][3], cs[0][3], C0.w + fr0_, C4.w + fr1_); \
    lse_upd2(cm[1][0], cs[1][0], C1.x + fr0_, C5.x + fr1_); \
    lse_upd2(cm[1][1], cs[1][1], C1.y + fr0_, C5.y + fr1_); \
    lse_upd2(cm[1][2], cs[1][2], C1.z + fr0_, C5.z + fr1_); \
    lse_upd2(cm[1][3], cs[1][3], C1.w + fr0_, C5.w + fr1_); \
    lse_upd2(cm[2][0], cs[2][0], C2.x + fr0_, C6.x + fr1_); \
    lse_upd2(cm[2][1], cs[2][1], C2.y + fr0_, C6.y + fr1_); \
    lse_upd2(cm[2][2], cs[2][2], C2.z + fr0_, C6.z + fr1_); \
    lse_upd2(cm[2][3], cs[2][3], C2.w + fr0_, C6.w + fr1_); \
    lse_upd2(cm[3][0], cs[3][0], C3.x + fr0_, C7.x + fr1_); \
    lse_upd2(cm[3][1], cs[3][1], C3.y + fr0_, C7.y + fr1_); \
    lse_upd2(cm[3][2], cs[3][2], C3.z + fr0_, C7.z + fr1_); \
    lse_upd2(cm[3][3], cs[3][3], C3.w + fr0_, C7.w + fr1_); \
}

__global__ __launch_bounds__(512, 2) void iter_fused(const float* __restrict__ S,
                                                     const float* __restrict__ g,
                                                     const float* __restrict__ logb2,
                                                     float* __restrict__ f,
                                                     float* __restrict__ pm) {
    __shared__ float gsh[NR];                        // 32 KB, staged once
    __shared__ float redm[2][2][8], reds[2][2][8];   // [sc&1][row-in-pair][wave]
    __shared__ float lbsh[CROWS];
    const int t = threadIdx.x;
    const int wv = t >> 6, lane = t & 63;
    const int chunk = blockIdx.x;
    const int r0 = chunk * CROWS;
    const int col0 = wv * 1024 + lane * 4;   // thread's base col (cols col0+it*256)

    if (t < CROWS) lbsh[t] = logb2[r0 + t];
    // stage g into LDS: 512 threads x 4 float4, coalesced
#pragma unroll
    for (int it = 0; it < 4; ++it) {
        float4 gv = *(const float4*)(g + t * 4 + it * 2048);
        *(float4*)&gsh[t * 4 + it * 2048] = gv;
    }

    // column accumulators for the thread's 16 owned columns (constant-indexed)
    float cm[4][4], cs[4][4];
#pragma unroll
    for (int it = 0; it < 4; ++it)
#pragma unroll
        for (int c = 0; c < 4; ++c) { cm[it][c] = -INFINITY; cs[it][c] = 0.0f; }

    const float* Sb = S + (size_t)r0 * NR + col0;
    float fmine = 0.0f;

    __syncthreads();   // gsh/lbsh ready (full drain OK: prologue only)

    // ping-pong state: 16 NAMED float4 (pure SSA — cannot be alloca'd)
    float4 a0, a1, a2, a3, a4, a5, a6, a7;
    float4 b0, b1, b2, b3, b4, b5, b6, b7;
    {   // prologue: rows 0,1 into a*
        const float* S0 = Sb;
        const float* S1 = Sb + (size_t)NR;
        a0 = *(const float4*)(S0 +   0); a1 = *(const float4*)(S0 + 256);
        a2 = *(const float4*)(S0 + 512); a3 = *(const float4*)(S0 + 768);
        a4 = *(const float4*)(S1 +   0); a5 = *(const float4*)(S1 + 256);
        a6 = *(const float4*)(S1 + 512); a7 = *(const float4*)(S1 + 768);
    }

    SUBCHUNK(0, 0, a0,a1,a2,a3,a4,a5,a6,a7, b0,b1,b2,b3,b4,b5,b6,b7)
    SUBCHUNK(1, 1, b0,b1,b2,b3,b4,b5,b6,b7, a0,a1,a2,a3,a4,a5,a6,a7)
    SUBCHUNK(2, 0, a0,a1,a2,a3,a4,a5,a6,a7, b0,b1,b2,b3,b4,b5,b6,b7)
    SUBCHUNK(3, 1, b0,b1,b2,b3,b4,b5,b6,b7, a0,a1,a2,a3,a4,a5,a6,a7)
    SUBCHUNK(4, 0, a0,a1,a2,a3,a4,a5,a6,a7, b0,b1,b2,b3,b4,b5,b6,b7)
    SUBCHUNK(5, 1, b0,b1,b2,b3,b4,b5,b6,b7, a0,a1,a2,a3,a4,a5,a6,a7)
    SUBCHUNK(6, 0, a0,a1,a2,a3,a4,a5,a6,a7, b0,b1,b2,b3,b4,b5,b6,b7)
    SUBCHUNK(7, 1, b0,b1,b2,b3,b4,b5,b6,b7, a0,a1,a2,a3,a4,a5,a6,a7)

    if (t < CROWS) f[r0 + t] = fmine;

    // write column partials for this chunk as a single float L = m + log2(s)
#pragma unroll
    for (int it = 0; it < 4; ++it) {
        float4 L;
        L.x = cm[it][0] + flog2(cs[it][0]);
        L.y = cm[it][1] + flog2(cs[it][1]);
        L.z = cm[it][2] + flog2(cs[it][2]);
        L.w = cm[it][3] + flog2(cs[it][3]);
        *(float4*)&pm[(size_t)chunk * NR + col0 + it * 256] = L;
    }
}

// ---------------- combine partials -> g (256 blocks, two-level LSE) ----------------
__global__ __launch_bounds__(256) void col_combine(const float* __restrict__ pm,
                                                   float* __restrict__ g,
                                                   float log_a2) {
    __shared__ float Lsh[8][32];
    const int cl = threadIdx.x & 31;       // column within block
    const int gp = threadIdx.x >> 5;       // chunk group (0..7), 64 chunks each
    const int col = blockIdx.x * 32 + cl;
    float m = -INFINITY, s = 0.0f;
#pragma unroll
    for (int ch = gp * 64; ch < gp * 64 + 64; ch += 4) {
        float l0 = pm[(size_t)(ch + 0) * NR + col];
        float l1 = pm[(size_t)(ch + 1) * NR + col];
        float l2 = pm[(size_t)(ch + 2) * NR + col];
        float l3 = pm[(size_t)(ch + 3) * NR + col];
        lse_upd4(m, s, l0, l1, l2, l3);
    }
    Lsh[gp][cl] = m + flog2(s);
    __syncthreads();
    if (gp == 0) {
        float mm = -INFINITY, ss = 0.0f;
        lse_upd4(mm, ss, Lsh[0][cl], Lsh[1][cl], Lsh[2][cl], Lsh[3][cl]);
        lse_upd4(mm, ss, Lsh[4][cl], Lsh[5][cl], Lsh[6][cl], Lsh[7][cl]);
        g[col] = log_a2 - (mm + flog2(ss));
    }
}

// ---------------- T = exp2(f + S + g), in place; global sum == 1 analytically ------
// note: no __restrict__ on S/out — they alias (in-place)
__global__ __launch_bounds__(256) void write_pass(const float* S,
                                                  const float* __restrict__ f,
                                                  const float* __restrict__ g,
                                                  float* out) {
    const int wv = threadIdx.x >> 6, lane = threadIdx.x & 63;
    const int row = blockIdx.x * 4 + wv;
    const float fi = f[row];
    const float4* Sr = (const float4*)(S + (size_t)row * NR);
    const float4* gr = (const float4*)g;
    float4* Or = (float4*)(out + (size_t)row * NR);
#pragma unroll 4
    for (int it = 0; it < NR / 256; ++it) {
        const int idx = it * 64 + lane;
        float4 sv = Sr[idx];
        float4 gv = gr[idx];
        float4 o;
        o.x = fexp2(fi + sv.x + gv.x);
        o.y = fexp2(fi + sv.y + gv.y);
        o.z = fexp2(fi + sv.z + gv.z);
        o.w = fexp2(fi + sv.w + gv.w);
        Or[idx] = o;
    }
}

extern "C" void kernel_launch(void* const* d_in, const int* in_sizes, int n_in,
                              void* d_out, int out_size, void* d_ws, size_t ws_size,
                              hipStream_t stream) {
    (void)in_sizes; (void)n_in; (void)out_size; (void)ws_size;
    const float* A  = (const float*)d_in[0];
    const float* Tk = (const float*)d_in[1];
    const float* Wq = (const float*)d_in[2];
    const float* bq = (const float*)d_in[3];
    const float* Wk = (const float*)d_in[4];
    const float* bk = (const float*)d_in[5];
    const float* W1 = (const float*)d_in[6];
    const float* b1 = (const float*)d_in[7];
    const float* W2 = (const float*)d_in[8];
    const float* b2 = (const float*)d_in[9];
    float* S  = (float*)d_out;           // 8192x8192 base-2 log_K lives in d_out
    float* ws = (float*)d_ws;
    float* qn     = ws; ws += NR;
    float* kn     = ws; ws += NR;
    float* logb2  = ws; ws += NR;
    float* logits = ws; ws += NR;
    float* f      = ws; ws += NR;
    float* g      = ws; ws += NR;
    float* pm     = ws; ws += (size_t)NBLK * NR;   // 16 MB
    float* q      = ws; ws += (size_t)NR * DIM;    // 8 MB
    float* k      = ws; ws += (size_t)NR * DIM;    // 8 MB
    // bf16 split arrays overlay pm (16.78 MB == 4 x NR*DIM ushorts): they are
    // dead once dist_mfma finishes, before the first iter_fused writes pm.
    ushort_t* qh = (ushort_t*)pm;
    ushort_t* ql = qh + (size_t)NR * DIM;
    ushort_t* kh = ql + (size_t)NR * DIM;
    ushort_t* kl = kh + (size_t)NR * DIM;

    const float log_a2 = -13.0f; // log2(1/8192 + 1e-20)

    init_zero<<<32, 256, 0, stream>>>(g);
    gemm_qk<<<dim3(128, 4), 256, 0, stream>>>(A, Wq, bq, q);
    gemm_qk<<<dim3(128, 4), 256, 0, stream>>>(Tk, Wk, bk, k);
    row_norm<<<NR, 64, 0, stream>>>(q, qn);
    row_norm<<<NR, 64, 0, stream>>>(k, kn);
    split_bf16<<<NR * DIM / 1024, 256, 0, stream>>>(q, qh, ql);
    split_bf16<<<NR * DIM / 1024, 256, 0, stream>>>(k, kh, kl);
    mlp_logits<<<NR, 128, 0, stream>>>(A, W1, b1, W2, b2, logits);
    softmax_logb<<<1, 1024, 0, stream>>>(logits, logb2);
    dist_mfma<<<dim3(64, 64), 256, 0, stream>>>(qh, ql, kh, kl, qn, kn, S);
    for (int it = 0; it < 50; ++it) {
        iter_fused<<<NBLK, 512, 0, stream>>>(S, g, logb2, f, pm);
        col_combine<<<NR / 32, 256, 0, stream>>>(pm, g, log_a2);
    }
    write_pass<<<NR / 4, 256, 0, stream>>>(S, f, g, S);
}

// Round 6
// 8330.494 us; speedup vs baseline: 1.7487x; 1.1742x over previous
//
#include <hip/hip_runtime.h>
#include <math.h>

#define NR 8192      // NA == NT
#define DIM 256
#define NBLK 512     // fused-kernel blocks == column-partial chunks (2 per CU)
#define CROWS 16     // rows per chunk
#define NSUB 8       // sub-chunks per chunk (2 rows each, reg ping-pong)
// 10 * log2(e): converts distances directly into base-2 log domain
#define SCALE2 14.426950408889634f

typedef unsigned short ushort_t;
typedef __attribute__((ext_vector_type(8))) short bfrag;   // 8 bf16 (4 VGPRs)
typedef __attribute__((ext_vector_type(4))) float facc;    // 4 fp32 acc

// v_exp_f32 / v_log_f32 are base-2 natively — use them raw
__device__ __forceinline__ float fexp2(float x) {
#if __has_builtin(__builtin_amdgcn_exp2f)
    return __builtin_amdgcn_exp2f(x);
#else
    return exp2f(x);
#endif
}
__device__ __forceinline__ float flog2(float x) {
#if __has_builtin(__builtin_amdgcn_logf)
    return __builtin_amdgcn_logf(x);
#else
    return log2f(x);
#endif
}

// base-2 online LSE combine
__device__ __forceinline__ void lse_comb2(float& m, float& s, float mo, float so) {
    float nm = fmaxf(m, mo);
    s = s * fexp2(m - nm) + so * fexp2(mo - nm);
    m = nm;
}

// grouped-4 online LSE update (1 tree-max + 1 correction exp per 4 values)
__device__ __forceinline__ void lse_upd4(float& m, float& s,
                                         float v0, float v1, float v2, float v3) {
    float m4 = fmaxf(fmaxf(v0, v1), fmaxf(v2, v3));
    float nm = fmaxf(m, m4);
    float e = fexp2(v0 - nm) + fexp2(v1 - nm) + fexp2(v2 - nm) + fexp2(v3 - nm);
    s = fmaf(s, fexp2(m - nm), e);
    m = nm;
}

// grouped-2 online LSE update
__device__ __forceinline__ void lse_upd2(float& m, float& s, float v0, float v1) {
    float m2 = fmaxf(v0, v1);
    float nm = fmaxf(m, m2);
    float e = fexp2(v0 - nm) + fexp2(v1 - nm);
    s = fmaf(s, fexp2(m - nm), e);
    m = nm;
}

// RNE float -> bf16 bits (manual: deterministic, no API variance)
__device__ __forceinline__ ushort_t f2bf(float x) {
    unsigned u = __float_as_uint(x);
    u += 0x7FFFu + ((u >> 16) & 1u);
    return (ushort_t)(u >> 16);
}
__device__ __forceinline__ float bf2f(ushort_t b) {
    return __uint_as_float(((unsigned)b) << 16);
}

// ---------------- init ----------------
__global__ void init_zero(float* __restrict__ g) {
    int t = blockIdx.x * 256 + threadIdx.x;
    if (t < NR) g[t] = 0.0f;
}

// ---------------- out[M,DIM] = A[M,DIM] @ W[DIM,DIM] + bias ----------------
__global__ __launch_bounds__(256) void gemm_qk(const float* __restrict__ A,
                                               const float* __restrict__ W,
                                               const float* __restrict__ bias,
                                               float* __restrict__ out) {
    __shared__ float As[16][68];
    __shared__ float Ws[16][68];
    const int t  = threadIdx.x;
    const int r0 = blockIdx.x * 64;
    const int c0 = blockIdx.y * 64;
    const int ty = t >> 4, tx = t & 15;
    const int arow = t >> 2;
    const int ak   = (t & 3) * 4;
    const int wrow = t >> 4;
    const int wcol = (t & 15) * 4;
    float acc[4][4] = {};
    for (int k0 = 0; k0 < DIM; k0 += 16) {
        float4 av = *(const float4*)(A + (size_t)(r0 + arow) * DIM + k0 + ak);
        float4 wv = *(const float4*)(W + (size_t)(k0 + wrow) * DIM + c0 + wcol);
        __syncthreads();
        As[ak + 0][arow] = av.x; As[ak + 1][arow] = av.y;
        As[ak + 2][arow] = av.z; As[ak + 3][arow] = av.w;
        *(float4*)&Ws[wrow][wcol] = wv;
        __syncthreads();
#pragma unroll
        for (int kk = 0; kk < 16; ++kk) {
            float4 a = *(const float4*)&As[kk][ty * 4];
            float4 b = *(const float4*)&Ws[kk][tx * 4];
            float aa[4] = {a.x, a.y, a.z, a.w};
            float bb[4] = {b.x, b.y, b.z, b.w};
#pragma unroll
            for (int i = 0; i < 4; ++i)
#pragma unroll
                for (int j = 0; j < 4; ++j)
                    acc[i][j] = fmaf(aa[i], bb[j], acc[i][j]);
        }
    }
#pragma unroll
    for (int i = 0; i < 4; ++i) {
        float4 o;
        o.x = acc[i][0] + bias[c0 + tx * 4 + 0];
        o.y = acc[i][1] + bias[c0 + tx * 4 + 1];
        o.z = acc[i][2] + bias[c0 + tx * 4 + 2];
        o.w = acc[i][3] + bias[c0 + tx * 4 + 3];
        *(float4*)(out + (size_t)(r0 + ty * 4 + i) * DIM + c0 + tx * 4) = o;
    }
}

// ---------------- row squared norms ----------------
__global__ __launch_bounds__(64) void row_norm(const float* __restrict__ x,
                                               float* __restrict__ out) {
    const int row = blockIdx.x, lane = threadIdx.x;
    float4 v = *(const float4*)(x + (size_t)row * DIM + lane * 4);
    float s = v.x * v.x + v.y * v.y + v.z * v.z + v.w * v.w;
#pragma unroll
    for (int off = 32; off > 0; off >>= 1) s += __shfl_xor(s, off);
    if (lane == 0) out[row] = s;
}

// ---------------- split fp32 -> bf16 hi + bf16 lo (lo = bf16(x - hi)) ----------------
__global__ __launch_bounds__(256) void split_bf16(const float* __restrict__ x,
                                                  ushort_t* __restrict__ hi,
                                                  ushort_t* __restrict__ lo) {
    const int idx = (blockIdx.x * 256 + threadIdx.x) * 4;
    float4 v = *(const float4*)(x + idx);
    ushort_t h0 = f2bf(v.x), h1 = f2bf(v.y), h2 = f2bf(v.z), h3 = f2bf(v.w);
    ushort4 hv = make_ushort4(h0, h1, h2, h3);
    ushort4 lv = make_ushort4(f2bf(v.x - bf2f(h0)), f2bf(v.y - bf2f(h1)),
                              f2bf(v.z - bf2f(h2)), f2bf(v.w - bf2f(h3)));
    *(ushort4*)(hi + idx) = hv;
    *(ushort4*)(lo + idx) = lv;
}

// ---------------- S = SCALE2*(qn_i + kn_j - 2*q_i.k_j) via split-bf16 MFMA ----------
__global__ __launch_bounds__(256) void dist_mfma(const ushort_t* __restrict__ qh,
                                                 const ushort_t* __restrict__ ql,
                                                 const ushort_t* __restrict__ kh,
                                                 const ushort_t* __restrict__ kl,
                                                 const float* __restrict__ qn,
                                                 const float* __restrict__ kn,
                                                 float* __restrict__ S) {
    const int t = threadIdx.x;
    const int wv = t >> 6, lane = t & 63;
    const int r0 = blockIdx.y * 128 + (wv >> 1) * 64;
    const int c0 = blockIdx.x * 128 + (wv & 1) * 64;
    const int fr = lane & 15;       // row (A) / col (B) within 16x16 tile
    const int fq = lane >> 4;       // quad -> k-subrange / C-row group
    facc acc[4][4];
#pragma unroll
    for (int i = 0; i < 4; ++i)
#pragma unroll
        for (int j = 0; j < 4; ++j) acc[i][j] = (facc){0.f, 0.f, 0.f, 0.f};

    for (int k0 = 0; k0 < DIM; k0 += 32) {
        const int ks = k0 + fq * 8;
        bfrag ah[4], al[4], bh[4], bl[4];
#pragma unroll
        for (int mi = 0; mi < 4; ++mi) {
            const size_t ao = (size_t)(r0 + mi * 16 + fr) * DIM + ks;
            ah[mi] = *(const bfrag*)(qh + ao);
            al[mi] = *(const bfrag*)(ql + ao);
        }
#pragma unroll
        for (int ni = 0; ni < 4; ++ni) {
            const size_t bo = (size_t)(c0 + ni * 16 + fr) * DIM + ks;
            bh[ni] = *(const bfrag*)(kh + bo);
            bl[ni] = *(const bfrag*)(kl + bo);
        }
#pragma unroll
        for (int mi = 0; mi < 4; ++mi)
#pragma unroll
            for (int ni = 0; ni < 4; ++ni) {
                acc[mi][ni] = __builtin_amdgcn_mfma_f32_16x16x32_bf16(ah[mi], bh[ni], acc[mi][ni], 0, 0, 0);
                acc[mi][ni] = __builtin_amdgcn_mfma_f32_16x16x32_bf16(ah[mi], bl[ni], acc[mi][ni], 0, 0, 0);
                acc[mi][ni] = __builtin_amdgcn_mfma_f32_16x16x32_bf16(al[mi], bh[ni], acc[mi][ni], 0, 0, 0);
                acc[mi][ni] = __builtin_amdgcn_mfma_f32_16x16x32_bf16(al[mi], bl[ni], acc[mi][ni], 0, 0, 0);
            }
    }
    // epilogue: S[row][col] = (qn + kn - 2*dot) * SCALE2
#pragma unroll
    for (int mi = 0; mi < 4; ++mi) {
        float qnr[4];
#pragma unroll
        for (int r = 0; r < 4; ++r) qnr[r] = qn[r0 + mi * 16 + fq * 4 + r];
#pragma unroll
        for (int ni = 0; ni < 4; ++ni) {
            const int col = c0 + ni * 16 + fr;
            const float knc = kn[col];
#pragma unroll
            for (int r = 0; r < 4; ++r) {
                const int row = r0 + mi * 16 + fq * 4 + r;
                S[(size_t)row * NR + col] = (qnr[r] + knc - 2.0f * acc[mi][ni][r]) * SCALE2;
            }
        }
    }
}

// ---------------- MLP logits: relu(A@W1+b1)@W2 + b2 ----------------
__global__ __launch_bounds__(128) void mlp_logits(const float* __restrict__ A,
                                                  const float* __restrict__ W1,
                                                  const float* __restrict__ b1,
                                                  const float* __restrict__ W2,
                                                  const float* __restrict__ b2,
                                                  float* __restrict__ logits) {
    __shared__ float ar[DIM];
    __shared__ float red[2];
    const int t = threadIdx.x;
    const int row = blockIdx.x;
    *(float2*)&ar[t * 2] = *(const float2*)(A + (size_t)row * DIM + t * 2);
    __syncthreads();
    float h = b1[t];
#pragma unroll 8
    for (int kk = 0; kk < DIM; ++kk) h = fmaf(ar[kk], W1[kk * 128 + t], h);
    float val = fmaxf(h, 0.0f) * W2[t];
#pragma unroll
    for (int off = 32; off > 0; off >>= 1) val += __shfl_xor(val, off);
    if ((t & 63) == 0) red[t >> 6] = val;
    __syncthreads();
    if (t == 0) logits[row] = red[0] + red[1] + b2[0];
}

// ---------------- softmax over 8192 logits -> log2(b + 1e-20) ----------------
__global__ __launch_bounds__(1024) void softmax_logb(const float* __restrict__ logits,
                                                     float* __restrict__ logb2) {
    __shared__ float redm[16], reds[16];
    const int t = threadIdx.x;
    float l[8];
    float m = -INFINITY;
#pragma unroll
    for (int i = 0; i < 8; ++i) { l[i] = logits[i * 1024 + t]; m = fmaxf(m, l[i]); }
#pragma unroll
    for (int off = 32; off > 0; off >>= 1) m = fmaxf(m, __shfl_xor(m, off));
    if ((t & 63) == 0) redm[t >> 6] = m;
    __syncthreads();
    if (t < 64) {
        float v = (t < 16) ? redm[t] : -INFINITY;
#pragma unroll
        for (int off = 8; off > 0; off >>= 1) v = fmaxf(v, __shfl_xor(v, off));
        if (t == 0) redm[0] = v;
    }
    __syncthreads();
    m = redm[0];
    float s = 0.0f;
#pragma unroll
    for (int i = 0; i < 8; ++i) s += __expf(l[i] - m);
#pragma unroll
    for (int off = 32; off > 0; off >>= 1) s += __shfl_xor(s, off);
    if ((t & 63) == 0) reds[t >> 6] = s;
    __syncthreads();
    if (t < 64) {
        float v = (t < 16) ? reds[t] : 0.0f;
#pragma unroll
        for (int off = 8; off > 0; off >>= 1) v += __shfl_xor(v, off);
        if (t == 0) reds[0] = v;
    }
    __syncthreads();
    s = reds[0];
    float invs = 1.0f / s;
#pragma unroll
    for (int i = 0; i < 8; ++i)
        logb2[i * 1024 + t] = log2f(__expf(l[i] - m) * invs + 1e-20f);
}

// ---------------- fused iteration: wave-aligned, register-direct, LDS-free S -------
// R5 post-mortem: launch_bounds(512,2) raised the VGPR cap to 128 but the live
// set still peaked ~130-140 (prefetch issued at macro top => cur+nxt+cm/cs all
// live through phase 1) -> residual allocator spill, iter ~170 us. This round:
// (a) prefetch ISSUE moved to after phase-1 reduce (fat region shrinks to the
//     barrier->phase-2 span; loads still get ~600 cyc of cover),
// (b) combine uses a chained running (M,P) pair per row (4 temps, not 16),
// (c) sched_barrier(0) before the prefetch so the scheduler can't hoist the
//     loads back into phase 1.
// Peak liveness est ~105 < 128. Everything else as R5 (named-SSA ping-pong,
// one raw lgkm-only barrier per sub-chunk, redm/reds double-buffered by sc&1).
#define SUBCHUNK(sc, pb, C0,C1,C2,C3,C4,C5,C6,C7, N0,N1,N2,N3,N4,N5,N6,N7) { \
    float m0_ = -INFINITY, s0_ = 0.0f, m1_ = -INFINITY, s1_ = 0.0f; \
    { \
        float4 gv0 = *(const float4*)&gsh[col0 +   0]; \
        lse_upd4(m0_, s0_, C0.x + gv0.x, C0.y + gv0.y, C0.z + gv0.z, C0.w + gv0.w); \
        lse_upd4(m1_, s1_, C4.x + gv0.x, C4.y + gv0.y, C4.z + gv0.z, C4.w + gv0.w); \
        float4 gv1 = *(const float4*)&gsh[col0 + 256]; \
        lse_upd4(m0_, s0_, C1.x + gv1.x, C1.y + gv1.y, C1.z + gv1.z, C1.w + gv1.w); \
        lse_upd4(m1_, s1_, C5.x + gv1.x, C5.y + gv1.y, C5.z + gv1.z, C5.w + gv1.w); \
        float4 gv2 = *(const float4*)&gsh[col0 + 512]; \
        lse_upd4(m0_, s0_, C2.x + gv2.x, C2.y + gv2.y, C2.z + gv2.z, C2.w + gv2.w); \
        lse_upd4(m1_, s1_, C6.x + gv2.x, C6.y + gv2.y, C6.z + gv2.z, C6.w + gv2.w); \
        float4 gv3 = *(const float4*)&gsh[col0 + 768]; \
        lse_upd4(m0_, s0_, C3.x + gv3.x, C3.y + gv3.y, C3.z + gv3.z, C3.w + gv3.w); \
        lse_upd4(m1_, s1_, C7.x + gv3.x, C7.y + gv3.y, C7.z + gv3.z, C7.w + gv3.w); \
    } \
    _Pragma("unroll") \
    for (int off_ = 32; off_ > 0; off_ >>= 1) { \
        float am_ = __shfl_xor(m0_, off_), as_ = __shfl_xor(s0_, off_); \
        lse_comb2(m0_, s0_, am_, as_); \
        float bm_ = __shfl_xor(m1_, off_), bs_ = __shfl_xor(s1_, off_); \
        lse_comb2(m1_, s1_, bm_, bs_); \
    } \
    if (lane == 0) { \
        redm[pb][0][wv] = m0_; reds[pb][0][wv] = s0_; \
        redm[pb][1][wv] = m1_; reds[pb][1][wv] = s1_; \
    } \
    __builtin_amdgcn_sched_barrier(0);  /* pin prefetch issue point */ \
    if ((sc) + 1 < NSUB) { \
        const float* Sn0 = Sb + (size_t)(2 * (sc) + 2) * NR; \
        const float* Sn1 = Sb + (size_t)(2 * (sc) + 3) * NR; \
        N0 = *(const float4*)(Sn0 +   0); N1 = *(const float4*)(Sn0 + 256); \
        N2 = *(const float4*)(Sn0 + 512); N3 = *(const float4*)(Sn0 + 768); \
        N4 = *(const float4*)(Sn1 +   0); N5 = *(const float4*)(Sn1 + 256); \
        N6 = *(const float4*)(Sn1 + 512); N7 = *(const float4*)(Sn1 + 768); \
    } \
    asm volatile("s_waitcnt lgkmcnt(0)" ::: "memory"); \
    __builtin_amdgcn_s_barrier(); \
    float M_ = redm[pb][0][0], P_ = reds[pb][0][0]; \
    lse_comb2(M_, P_, redm[pb][0][1], reds[pb][0][1]); \
    lse_comb2(M_, P_, redm[pb][0][2], reds[pb][0][2]); \
    lse_comb2(M_, P_, redm[pb][0][3], reds[pb][0][3]); \
    lse_comb2(M_, P_, redm[pb][0][4], reds[pb][0][4]); \
    lse_comb2(M_, P_, redm[pb][0][5], reds[pb][0][5]); \
    lse_comb2(M_, P_, redm[pb][0][6], reds[pb][0][6]); \
    lse_comb2(M_, P_, redm[pb][0][7], reds[pb][0][7]); \
    const float fr0_ = lbsh[2 * (sc) + 0] - (M_ + flog2(P_)); \
    M_ = redm[pb][1][0]; P_ = reds[pb][1][0]; \
    lse_comb2(M_, P_, redm[pb][1][1], reds[pb][1][1]); \
    lse_comb2(M_, P_, redm[pb][1][2], reds[pb][1][2]); \
    lse_comb2(M_, P_, redm[pb][1][3], reds[pb][1][3]); \
    lse_comb2(M_, P_, redm[pb][1][4], reds[pb][1][4]); \
    lse_comb2(M_, P_, redm[pb][1][5], reds[pb][1][5]); \
    lse_comb2(M_, P_, redm[pb][1][6], reds[pb][1][6]); \
    lse_comb2(M_, P_, redm[pb][1][7], reds[pb][1][7]); \
    const float fr1_ = lbsh[2 * (sc) + 1] - (M_ + flog2(P_)); \
    if (t == 2 * (sc))     fmine = fr0_; \
    if (t == 2 * (sc) + 1) fmine = fr1_; \
    lse_upd2(cm[0][0], cs[0][0], C0.x + fr0_, C4.x + fr1_); \
    lse_upd2(cm[0][1], cs[0][1], C0.y + fr0_, C4.y + fr1_); \
    lse_upd2(cm[0][2], cs[0][2], C0.z + fr0_, C4.z + fr1_); \
    lse_upd2(cm[0][3], cs[0][3], C0.w + fr0_, C4.w + fr1_); \
    lse_upd2(cm[1][0], cs[1][0], C1.x + fr0_, C5.x + fr1_); \
    lse_upd2(cm[1][1], cs[1][1], C1.y + fr0_, C5.y + fr1_); \
    lse_upd2(cm[1][2], cs[1][2], C1.z + fr0_, C5.z + fr1_); \
    lse_upd2(cm[1][3], cs[1][3], C1.w + fr0_, C5.w + fr1_); \
    lse_upd2(cm[2][0], cs[2][0], C2.x + fr0_, C6.x + fr1_); \
    lse_upd2(cm[2][1], cs[2][1], C2.y + fr0_, C6.y + fr1_); \
    lse_upd2(cm[2][2], cs[2][2], C2.z + fr0_, C6.z + fr1_); \
    lse_upd2(cm[2][3], cs[2][3], C2.w + fr0_, C6.w + fr1_); \
    lse_upd2(cm[3][0], cs[3][0], C3.x + fr0_, C7.x + fr1_); \
    lse_upd2(cm[3][1], cs[3][1], C3.y + fr0_, C7.y + fr1_); \
    lse_upd2(cm[3][2], cs[3][2], C3.z + fr0_, C7.z + fr1_); \
    lse_upd2(cm[3][3], cs[3][3], C3.w + fr0_, C7.w + fr1_); \
}

__global__ __launch_bounds__(512, 2) void iter_fused(const float* __restrict__ S,
                                                     const float* __restrict__ g,
                                                     const float* __restrict__ logb2,
                                                     float* __restrict__ f,
                                                     float* __restrict__ pm) {
    __shared__ float gsh[NR];                        // 32 KB, staged once
    __shared__ float redm[2][2][8], reds[2][2][8];   // [sc&1][row-in-pair][wave]
    __shared__ float lbsh[CROWS];
    const int t = threadIdx.x;
    const int wv = t >> 6, lane = t & 63;
    const int chunk = blockIdx.x;
    const int r0 = chunk * CROWS;
    const int col0 = wv * 1024 + lane * 4;   // thread's base col (cols col0+it*256)

    if (t < CROWS) lbsh[t] = logb2[r0 + t];
    // stage g into LDS: 512 threads x 4 float4, coalesced
#pragma unroll
    for (int it = 0; it < 4; ++it) {
        float4 gv = *(const float4*)(g + t * 4 + it * 2048);
        *(float4*)&gsh[t * 4 + it * 2048] = gv;
    }

    // column accumulators for the thread's 16 owned columns (constant-indexed)
    float cm[4][4], cs[4][4];
#pragma unroll
    for (int it = 0; it < 4; ++it)
#pragma unroll
        for (int c = 0; c < 4; ++c) { cm[it][c] = -INFINITY; cs[it][c] = 0.0f; }

    const float* Sb = S + (size_t)r0 * NR + col0;
    float fmine = 0.0f;

    __syncthreads();   // gsh/lbsh ready (full drain OK: prologue only)

    // ping-pong state: 16 NAMED float4 (pure SSA — cannot be alloca'd)
    float4 a0, a1, a2, a3, a4, a5, a6, a7;
    float4 b0, b1, b2, b3, b4, b5, b6, b7;
    {   // prologue: rows 0,1 into a*
        const float* S0 = Sb;
        const float* S1 = Sb + (size_t)NR;
        a0 = *(const float4*)(S0 +   0); a1 = *(const float4*)(S0 + 256);
        a2 = *(const float4*)(S0 + 512); a3 = *(const float4*)(S0 + 768);
        a4 = *(const float4*)(S1 +   0); a5 = *(const float4*)(S1 + 256);
        a6 = *(const float4*)(S1 + 512); a7 = *(const float4*)(S1 + 768);
    }

    SUBCHUNK(0, 0, a0,a1,a2,a3,a4,a5,a6,a7, b0,b1,b2,b3,b4,b5,b6,b7)
    SUBCHUNK(1, 1, b0,b1,b2,b3,b4,b5,b6,b7, a0,a1,a2,a3,a4,a5,a6,a7)
    SUBCHUNK(2, 0, a0,a1,a2,a3,a4,a5,a6,a7, b0,b1,b2,b3,b4,b5,b6,b7)
    SUBCHUNK(3, 1, b0,b1,b2,b3,b4,b5,b6,b7, a0,a1,a2,a3,a4,a5,a6,a7)
    SUBCHUNK(4, 0, a0,a1,a2,a3,a4,a5,a6,a7, b0,b1,b2,b3,b4,b5,b6,b7)
    SUBCHUNK(5, 1, b0,b1,b2,b3,b4,b5,b6,b7, a0,a1,a2,a3,a4,a5,a6,a7)
    SUBCHUNK(6, 0, a0,a1,a2,a3,a4,a5,a6,a7, b0,b1,b2,b3,b4,b5,b6,b7)
    SUBCHUNK(7, 1, b0,b1,b2,b3,b4,b5,b6,b7, a0,a1,a2,a3,a4,a5,a6,a7)

    if (t < CROWS) f[r0 + t] = fmine;

    // write column partials for this chunk as a single float L = m + log2(s)
#pragma unroll
    for (int it = 0; it < 4; ++it) {
        float4 L;
        L.x = cm[it][0] + flog2(cs[it][0]);
        L.y = cm[it][1] + flog2(cs[it][1]);
        L.z = cm[it][2] + flog2(cs[it][2]);
        L.w = cm[it][3] + flog2(cs[it][3]);
        *(float4*)&pm[(size_t)chunk * NR + col0 + it * 256] = L;
    }
}

// ---------------- combine partials -> g (256 blocks, two-level LSE) ----------------
__global__ __launch_bounds__(256) void col_combine(const float* __restrict__ pm,
                                                   float* __restrict__ g,
                                                   float log_a2) {
    __shared__ float Lsh[8][32];
    const int cl = threadIdx.x & 31;       // column within block
    const int gp = threadIdx.x >> 5;       // chunk group (0..7), 64 chunks each
    const int col = blockIdx.x * 32 + cl;
    float m = -INFINITY, s = 0.0f;
#pragma unroll
    for (int ch = gp * 64; ch < gp * 64 + 64; ch += 4) {
        float l0 = pm[(size_t)(ch + 0) * NR + col];
        float l1 = pm[(size_t)(ch + 1) * NR + col];
        float l2 = pm[(size_t)(ch + 2) * NR + col];
        float l3 = pm[(size_t)(ch + 3) * NR + col];
        lse_upd4(m, s, l0, l1, l2, l3);
    }
    Lsh[gp][cl] = m + flog2(s);
    __syncthreads();
    if (gp == 0) {
        float mm = -INFINITY, ss = 0.0f;
        lse_upd4(mm, ss, Lsh[0][cl], Lsh[1][cl], Lsh[2][cl], Lsh[3][cl]);
        lse_upd4(mm, ss, Lsh[4][cl], Lsh[5][cl], Lsh[6][cl], Lsh[7][cl]);
        g[col] = log_a2 - (mm + flog2(ss));
    }
}

// ---------------- T = exp2(f + S + g), in place; global sum == 1 analytically ------
// note: no __restrict__ on S/out — they alias (in-place)
__global__ __launch_bounds__(256) void write_pass(const float* S,
                                                  const float* __restrict__ f,
                                                  const float* __restrict__ g,
                                                  float* out) {
    const int wv = threadIdx.x >> 6, lane = threadIdx.x & 63;
    const int row = blockIdx.x * 4 + wv;
    const float fi = f[row];
    const float4* Sr = (const float4*)(S + (size_t)row * NR);
    const float4* gr = (const float4*)g;
    float4* Or = (float4*)(out + (size_t)row * NR);
#pragma unroll 4
    for (int it = 0; it < NR / 256; ++it) {
        const int idx = it * 64 + lane;
        float4 sv = Sr[idx];
        float4 gv = gr[idx];
        float4 o;
        o.x = fexp2(fi + sv.x + gv.x);
        o.y = fexp2(fi + sv.y + gv.y);
        o.z = fexp2(fi + sv.z + gv.z);
        o.w = fexp2(fi + sv.w + gv.w);
        Or[idx] = o;
    }
}

extern "C" void kernel_launch(void* const* d_in, const int* in_sizes, int n_in,
                              void* d_out, int out_size, void* d_ws, size_t ws_size,
                              hipStream_t stream) {
    (void)in_sizes; (void)n_in; (void)out_size; (void)ws_size;
    const float* A  = (const float*)d_in[0];
    const float* Tk = (const float*)d_in[1];
    const float* Wq = (const float*)d_in[2];
    const float* bq = (const float*)d_in[3];
    const float* Wk = (const float*)d_in[4];
    const float* bk = (const float*)d_in[5];
    const float* W1 = (const float*)d_in[6];
    const float* b1 = (const float*)d_in[7];
    const float* W2 = (const float*)d_in[8];
    const float* b2 = (const float*)d_in[9];
    float* S  = (float*)d_out;           // 8192x8192 base-2 log_K lives in d_out
    float* ws = (float*)d_ws;
    float* qn     = ws; ws += NR;
    float* kn     = ws; ws += NR;
    float* logb2  = ws; ws += NR;
    float* logits = ws; ws += NR;
    float* f      = ws; ws += NR;
    float* g      = ws; ws += NR;
    float* pm     = ws; ws += (size_t)NBLK * NR;   // 16 MB
    float* q      = ws; ws += (size_t)NR * DIM;    // 8 MB
    float* k      = ws; ws += (size_t)NR * DIM;    // 8 MB
    // bf16 split arrays overlay pm (16.78 MB == 4 x NR*DIM ushorts): they are
    // dead once dist_mfma finishes, before the first iter_fused writes pm.
    ushort_t* qh = (ushort_t*)pm;
    ushort_t* ql = qh + (size_t)NR * DIM;
    ushort_t* kh = ql + (size_t)NR * DIM;
    ushort_t* kl = kh + (size_t)NR * DIM;

    const float log_a2 = -13.0f; // log2(1/8192 + 1e-20)

    init_zero<<<32, 256, 0, stream>>>(g);
    gemm_qk<<<dim3(128, 4), 256, 0, stream>>>(A, Wq, bq, q);
    gemm_qk<<<dim3(128, 4), 256, 0, stream>>>(Tk, Wk, bk, k);
    row_norm<<<NR, 64, 0, stream>>>(q, qn);
    row_norm<<<NR, 64, 0, stream>>>(k, kn);
    split_bf16<<<NR * DIM / 1024, 256, 0, stream>>>(q, qh, ql);
    split_bf16<<<NR * DIM / 1024, 256, 0, stream>>>(k, kh, kl);
    mlp_logits<<<NR, 128, 0, stream>>>(A, W1, b1, W2, b2, logits);
    softmax_logb<<<1, 1024, 0, stream>>>(logits, logb2);
    dist_mfma<<<dim3(64, 64), 256, 0, stream>>>(qh, ql, kh, kl, qn, kn, S);
    for (int it = 0; it < 50; ++it) {
        iter_fused<<<NBLK, 512, 0, stream>>>(S, g, logb2, f, pm);
        col_combine<<<NR / 32, 256, 0, stream>>>(pm, g, log_a2);
    }
    write_pass<<<NR / 4, 256, 0, stream>>>(S, f, g, S);
}

// Round 8
// 3428.265 us; speedup vs baseline: 4.2493x; 2.4299x over previous
//
#include <hip/hip_runtime.h>
#include <math.h>

#define NR 8192      // NA == NT
#define DIM 256
#define NBLK 512     // fused-kernel blocks == column-partial chunks (2 per CU)
#define CROWS 16     // rows per chunk
#define RSC 2        // rows per sub-chunk
#define NSUB 8       // sub-chunks per chunk
// 10 * log2(e): converts distances directly into base-2 log domain
#define SCALE2 14.426950408889634f

typedef unsigned short ushort_t;
typedef __attribute__((ext_vector_type(8))) short bfrag;   // 8 bf16 (4 VGPRs)
typedef __attribute__((ext_vector_type(4))) float facc;    // 4 fp32 acc

// v_exp_f32 / v_log_f32 are base-2 natively — use them raw
__device__ __forceinline__ float fexp2(float x) {
#if __has_builtin(__builtin_amdgcn_exp2f)
    return __builtin_amdgcn_exp2f(x);
#else
    return exp2f(x);
#endif
}
__device__ __forceinline__ float flog2(float x) {
#if __has_builtin(__builtin_amdgcn_logf)
    return __builtin_amdgcn_logf(x);
#else
    return log2f(x);
#endif
}

// async global->LDS copy, 16 B per lane, no transit VGPRs.
__device__ __forceinline__ void gl2lds16(const float* gp, float* lp) {
#if __has_builtin(__builtin_amdgcn_global_load_lds)
    __builtin_amdgcn_global_load_lds(
        (const __attribute__((address_space(1))) unsigned int*)gp,
        (__attribute__((address_space(3))) unsigned int*)lp, 16, 0, 0);
#else
    *(float4*)lp = *(const float4*)gp;   // fallback: callers pass lane-adjusted ptrs
#endif
}

// raw waits/barrier: barrier WITHOUT vmcnt(0) drain; explicit vmcnt gate.
__device__ __forceinline__ void wait_vm0()  { asm volatile("s_waitcnt vmcnt(0)" ::: "memory"); }
__device__ __forceinline__ void bar_lgkm()  { asm volatile("s_waitcnt lgkmcnt(0)\ns_barrier" ::: "memory"); }

// base-2 online LSE combine
__device__ __forceinline__ void lse_comb2(float& m, float& s, float mo, float so) {
    float nm = fmaxf(m, mo);
    s = s * fexp2(m - nm) + so * fexp2(mo - nm);
    m = nm;
}

// grouped-4 online LSE update (1 tree-max + 1 correction exp per 4 values)
__device__ __forceinline__ void lse_upd4(float& m, float& s,
                                         float v0, float v1, float v2, float v3) {
    float m4 = fmaxf(fmaxf(v0, v1), fmaxf(v2, v3));
    float nm = fmaxf(m, m4);
    float e = fexp2(v0 - nm) + fexp2(v1 - nm) + fexp2(v2 - nm) + fexp2(v3 - nm);
    s = fmaf(s, fexp2(m - nm), e);
    m = nm;
}

// grouped-2 online LSE update
__device__ __forceinline__ void lse_upd2(float& m, float& s, float v0, float v1) {
    float m2 = fmaxf(v0, v1);
    float nm = fmaxf(m, m2);
    float e = fexp2(v0 - nm) + fexp2(v1 - nm);
    s = fmaf(s, fexp2(m - nm), e);
    m = nm;
}

// RNE float -> bf16 bits (manual: deterministic, no API variance)
__device__ __forceinline__ ushort_t f2bf(float x) {
    unsigned u = __float_as_uint(x);
    u += 0x7FFFu + ((u >> 16) & 1u);
    return (ushort_t)(u >> 16);
}
__device__ __forceinline__ float bf2f(ushort_t b) {
    return __uint_as_float(((unsigned)b) << 16);
}

// ---------------- init ----------------
__global__ void init_zero(float* __restrict__ g) {
    int t = blockIdx.x * 256 + threadIdx.x;
    if (t < NR) g[t] = 0.0f;
}

// ---------------- out[M,DIM] = A[M,DIM] @ W[DIM,DIM] + bias (2 problems, z-dim) ----
__global__ __launch_bounds__(256) void gemm_qk2(const float* __restrict__ A0,
                                                const float* __restrict__ W0,
                                                const float* __restrict__ bias0,
                                                float* __restrict__ out0,
                                                const float* __restrict__ A1,
                                                const float* __restrict__ W1,
                                                const float* __restrict__ bias1,
                                                float* __restrict__ out1) {
    const float* A    = blockIdx.z ? A1 : A0;
    const float* W    = blockIdx.z ? W1 : W0;
    const float* bias = blockIdx.z ? bias1 : bias0;
    float* out        = blockIdx.z ? out1 : out0;
    __shared__ float As[16][68];
    __shared__ float Ws[16][68];
    const int t  = threadIdx.x;
    const int r0 = blockIdx.x * 64;
    const int c0 = blockIdx.y * 64;
    const int ty = t >> 4, tx = t & 15;
    const int arow = t >> 2;
    const int ak   = (t & 3) * 4;
    const int wrow = t >> 4;
    const int wcol = (t & 15) * 4;
    float acc[4][4] = {};
    for (int k0 = 0; k0 < DIM; k0 += 16) {
        float4 av = *(const float4*)(A + (size_t)(r0 + arow) * DIM + k0 + ak);
        float4 wv = *(const float4*)(W + (size_t)(k0 + wrow) * DIM + c0 + wcol);
        __syncthreads();
        As[ak + 0][arow] = av.x; As[ak + 1][arow] = av.y;
        As[ak + 2][arow] = av.z; As[ak + 3][arow] = av.w;
        *(float4*)&Ws[wrow][wcol] = wv;
        __syncthreads();
#pragma unroll
        for (int kk = 0; kk < 16; ++kk) {
            float4 a = *(const float4*)&As[kk][ty * 4];
            float4 b = *(const float4*)&Ws[kk][tx * 4];
            float aa[4] = {a.x, a.y, a.z, a.w};
            float bb[4] = {b.x, b.y, b.z, b.w};
#pragma unroll
            for (int i = 0; i < 4; ++i)
#pragma unroll
                for (int j = 0; j < 4; ++j)
                    acc[i][j] = fmaf(aa[i], bb[j], acc[i][j]);
        }
    }
#pragma unroll
    for (int i = 0; i < 4; ++i) {
        float4 o;
        o.x = acc[i][0] + bias[c0 + tx * 4 + 0];
        o.y = acc[i][1] + bias[c0 + tx * 4 + 1];
        o.z = acc[i][2] + bias[c0 + tx * 4 + 2];
        o.w = acc[i][3] + bias[c0 + tx * 4 + 3];
        *(float4*)(out + (size_t)(r0 + ty * 4 + i) * DIM + c0 + tx * 4) = o;
    }
}

// ---------------- row squared norms (q and k in one launch) ----------------
__global__ __launch_bounds__(64) void row_norm2(const float* __restrict__ q,
                                                float* __restrict__ qn,
                                                const float* __restrict__ k,
                                                float* __restrict__ kn) {
    const int sel = blockIdx.x >> 13;          // 0: q, 1: k (8192 blocks each)
    const int row = blockIdx.x & (NR - 1);
    const int lane = threadIdx.x;
    const float* x = sel ? k : q;
    float* out     = sel ? kn : qn;
    float4 v = *(const float4*)(x + (size_t)row * DIM + lane * 4);
    float s = v.x * v.x + v.y * v.y + v.z * v.z + v.w * v.w;
#pragma unroll
    for (int off = 32; off > 0; off >>= 1) s += __shfl_xor(s, off);
    if (lane == 0) out[row] = s;
}

// ---------------- split fp32 -> bf16 hi + lo, q and k in one launch --------------
__global__ __launch_bounds__(256) void split_bf16_2(const float* __restrict__ q,
                                                    ushort_t* __restrict__ qh,
                                                    ushort_t* __restrict__ ql,
                                                    const float* __restrict__ k,
                                                    ushort_t* __restrict__ kh,
                                                    ushort_t* __restrict__ kl) {
    const int sel = blockIdx.x >> 11;          // 2048 blocks per problem
    const int b = blockIdx.x & 2047;
    const float* x = sel ? k : q;
    ushort_t* hi   = sel ? kh : qh;
    ushort_t* lo   = sel ? kl : ql;
    const int idx = (b * 256 + threadIdx.x) * 4;
    float4 v = *(const float4*)(x + idx);
    ushort_t h0 = f2bf(v.x), h1 = f2bf(v.y), h2 = f2bf(v.z), h3 = f2bf(v.w);
    ushort4 hv = make_ushort4(h0, h1, h2, h3);
    ushort4 lv = make_ushort4(f2bf(v.x - bf2f(h0)), f2bf(v.y - bf2f(h1)),
                              f2bf(v.z - bf2f(h2)), f2bf(v.w - bf2f(h3)));
    *(ushort4*)(hi + idx) = hv;
    *(ushort4*)(lo + idx) = lv;
}

// ---------------- S = SCALE2*(qn_i + kn_j - 2*q_i.k_j) via split-bf16 MFMA ----------
// 4096 blocks x 256 threads (4 waves, 2x2 of 64x64). mfma_f32_16x16x32_bf16:
// A[m=lane&15][k=quad*8+j], B[n=lane&15][k=quad*8+j] -> contiguous 16 B/lane loads
// straight from global (row-major bf16, L2/L3-served). Full 4-product split
// (hh+hl+lh+ll): per-element error <= 2^-19 — adds ~4e-4 exponent error,
// negligible vs the ~1e-2 LSE accumulation error. C/D: col=lane&15,
// row=quad*4+reg (m89-verified).
__global__ __launch_bounds__(256) void dist_mfma(const ushort_t* __restrict__ qh,
                                                 const ushort_t* __restrict__ ql,
                                                 const ushort_t* __restrict__ kh,
                                                 const ushort_t* __restrict__ kl,
                                                 const float* __restrict__ qn,
                                                 const float* __restrict__ kn,
                                                 float* __restrict__ S) {
    const int t = threadIdx.x;
    const int wv = t >> 6, lane = t & 63;
    const int r0 = blockIdx.y * 128 + (wv >> 1) * 64;
    const int c0 = blockIdx.x * 128 + (wv & 1) * 64;
    const int fr = lane & 15;       // row (A) / col (B) within 16x16 tile
    const int fq = lane >> 4;       // quad -> k-subrange / C-row group
    facc acc[4][4];
#pragma unroll
    for (int i = 0; i < 4; ++i)
#pragma unroll
        for (int j = 0; j < 4; ++j) acc[i][j] = (facc){0.f, 0.f, 0.f, 0.f};

    for (int k0 = 0; k0 < DIM; k0 += 32) {
        const int ks = k0 + fq * 8;
        bfrag ah[4], al[4], bh[4], bl[4];
#pragma unroll
        for (int mi = 0; mi < 4; ++mi) {
            const size_t ao = (size_t)(r0 + mi * 16 + fr) * DIM + ks;
            ah[mi] = *(const bfrag*)(qh + ao);
            al[mi] = *(const bfrag*)(ql + ao);
        }
#pragma unroll
        for (int ni = 0; ni < 4; ++ni) {
            const size_t bo = (size_t)(c0 + ni * 16 + fr) * DIM + ks;
            bh[ni] = *(const bfrag*)(kh + bo);
            bl[ni] = *(const bfrag*)(kl + bo);
        }
#pragma unroll
        for (int mi = 0; mi < 4; ++mi)
#pragma unroll
            for (int ni = 0; ni < 4; ++ni) {
                acc[mi][ni] = __builtin_amdgcn_mfma_f32_16x16x32_bf16(ah[mi], bh[ni], acc[mi][ni], 0, 0, 0);
                acc[mi][ni] = __builtin_amdgcn_mfma_f32_16x16x32_bf16(ah[mi], bl[ni], acc[mi][ni], 0, 0, 0);
                acc[mi][ni] = __builtin_amdgcn_mfma_f32_16x16x32_bf16(al[mi], bh[ni], acc[mi][ni], 0, 0, 0);
                acc[mi][ni] = __builtin_amdgcn_mfma_f32_16x16x32_bf16(al[mi], bl[ni], acc[mi][ni], 0, 0, 0);
            }
    }
    // epilogue: S[row][col] = (qn + kn - 2*dot) * SCALE2
#pragma unroll
    for (int mi = 0; mi < 4; ++mi) {
        float qnr[4];
#pragma unroll
        for (int r = 0; r < 4; ++r) qnr[r] = qn[r0 + mi * 16 + fq * 4 + r];
#pragma unroll
        for (int ni = 0; ni < 4; ++ni) {
            const int col = c0 + ni * 16 + fr;
            const float knc = kn[col];
#pragma unroll
            for (int r = 0; r < 4; ++r) {
                const int row = r0 + mi * 16 + fq * 4 + r;
                S[(size_t)row * NR + col] = (qnr[r] + knc - 2.0f * acc[mi][ni][r]) * SCALE2;
            }
        }
    }
}

// ---------------- MLP logits: relu(A@W1+b1)@W2 + b2 ----------------
__global__ __launch_bounds__(128) void mlp_logits(const float* __restrict__ A,
                                                  const float* __restrict__ W1,
                                                  const float* __restrict__ b1,
                                                  const float* __restrict__ W2,
                                                  const float* __restrict__ b2,
                                                  float* __restrict__ logits) {
    __shared__ float ar[DIM];
    __shared__ float red[2];
    const int t = threadIdx.x;
    const int row = blockIdx.x;
    *(float2*)&ar[t * 2] = *(const float2*)(A + (size_t)row * DIM + t * 2);
    __syncthreads();
    float h = b1[t];
#pragma unroll 8
    for (int kk = 0; kk < DIM; ++kk) h = fmaf(ar[kk], W1[kk * 128 + t], h);
    float val = fmaxf(h, 0.0f) * W2[t];
#pragma unroll
    for (int off = 32; off > 0; off >>= 1) val += __shfl_xor(val, off);
    if ((t & 63) == 0) red[t >> 6] = val;
    __syncthreads();
    if (t == 0) logits[row] = red[0] + red[1] + b2[0];
}

// ---------------- softmax over 8192 logits -> log2(b + 1e-20) ----------------
__global__ __launch_bounds__(1024) void softmax_logb(const float* __restrict__ logits,
                                                     float* __restrict__ logb2) {
    __shared__ float redm[16], reds[16];
    const int t = threadIdx.x;
    float l[8];
    float m = -INFINITY;
#pragma unroll
    for (int i = 0; i < 8; ++i) { l[i] = logits[i * 1024 + t]; m = fmaxf(m, l[i]); }
#pragma unroll
    for (int off = 32; off > 0; off >>= 1) m = fmaxf(m, __shfl_xor(m, off));
    if ((t & 63) == 0) redm[t >> 6] = m;
    __syncthreads();
    if (t < 64) {
        float v = (t < 16) ? redm[t] : -INFINITY;
#pragma unroll
        for (int off = 8; off > 0; off >>= 1) v = fmaxf(v, __shfl_xor(v, off));
        if (t == 0) redm[0] = v;
    }
    __syncthreads();
    m = redm[0];
    float s = 0.0f;
#pragma unroll
    for (int i = 0; i < 8; ++i) s += __expf(l[i] - m);
#pragma unroll
    for (int off = 32; off > 0; off >>= 1) s += __shfl_xor(s, off);
    if ((t & 63) == 0) reds[t >> 6] = s;
    __syncthreads();
    if (t < 64) {
        float v = (t < 16) ? reds[t] : 0.0f;
#pragma unroll
        for (int off = 8; off > 0; off >>= 1) v += __shfl_xor(v, off);
        if (t == 0) reds[0] = v;
    }
    __syncthreads();
    s = reds[0];
    float invs = 1.0f / s;
#pragma unroll
    for (int i = 0; i < 8; ++i)
        logb2[i * 1024 + t] = log2f(__expf(l[i] - m) * invs + 1e-20f);
}

// ---------------- fused iteration: DMA staging + 2 blocks/CU overlap ----------------
// (R0-proven structure: 54 us/iter, VGPR=64, zero scratch. Restored verbatim
// after R1-R6 showed both the row-granular dbuf and the register-direct
// variants lose to it — extra barriers/VALU in the former, allocator spill in
// the latter.)
__global__ __launch_bounds__(512, 4) void iter_fused(const float* __restrict__ S,
                                                     const float* __restrict__ g,
                                                     const float* __restrict__ logb2,
                                                     float* __restrict__ f,
                                                     float* __restrict__ pm) {
    __shared__ float buf[RSC][NR];      // 64 KB staging (single buffer)
    __shared__ float redm[8], reds[8];
    const int t = threadIdx.x;
    const int wv = t >> 6, lane = t & 63;
    const int chunk = blockIdx.x;
    const int r0 = chunk * CROWS;
    const int rw = wv >> 2;             // row (0..1) within sub-chunk
    const int qt = wv & 3;              // quarter of the row this wave handles
    const int qbase = qt * 2048;
    const int loff = lane * 4;

    // preload this wave's g quarter (constant within one launch): 8 float4
    float4 greg[8];
#pragma unroll
    for (int it = 0; it < 8; ++it)
        greg[it] = *(const float4*)(g + qbase + it * 256 + loff);

    // column accumulators: thread t owns cols {j*2048 + t*4 + c}
    float cm[4][4], cs[4][4];
#pragma unroll
    for (int j = 0; j < 4; ++j)
#pragma unroll
        for (int c = 0; c < 4; ++c) { cm[j][c] = -INFINITY; cs[j][c] = 0.0f; }

    // prologue: DMA sub-chunk 0
    {
        const float* Sr = S + (size_t)(r0 + rw) * NR + qbase;
        float* ld = &buf[rw][qbase];
#pragma unroll
        for (int it = 0; it < 8; ++it)
#if __has_builtin(__builtin_amdgcn_global_load_lds)
            gl2lds16(Sr + it * 256 + loff, ld + it * 256);
#else
            gl2lds16(Sr + it * 256 + loff, ld + it * 256 + loff);
#endif
    }

    for (int sc = 0; sc < NSUB; ++sc) {
        wait_vm0();   // own DMA(sc) (and greg/f stragglers) complete
        // ---- phase 1: row-LSE over this wave's quarter (LDS + g regs) ----
        float m = -INFINITY, s = 0.0f;
#pragma unroll
        for (int it = 0; it < 8; ++it) {
            float4 v = *(const float4*)&buf[rw][qbase + it * 256 + loff];
            float4 gv = greg[it];
            lse_upd4(m, s, v.x + gv.x, v.y + gv.y, v.z + gv.z, v.w + gv.w);
        }
#pragma unroll
        for (int off = 32; off > 0; off >>= 1) {
            float mo = __shfl_xor(m, off);
            float so = __shfl_xor(s, off);
            lse_comb2(m, s, mo, so);
        }
        if (lane == 0) { redm[wv] = m; reds[wv] = s; }
        bar_lgkm();   // barrier A: all DMA(sc) complete block-wide; red visible

        // ---- all threads: combine 4 quarter partials per row -> f0, f1 ----
        float fr[RSC];
#pragma unroll
        for (int r = 0; r < RSC; ++r) {
            float mm = redm[r * 4 + 0], ss = reds[r * 4 + 0];
            lse_comb2(mm, ss, redm[r * 4 + 1], reds[r * 4 + 1]);
            lse_comb2(mm, ss, redm[r * 4 + 2], reds[r * 4 + 2]);
            lse_comb2(mm, ss, redm[r * 4 + 3], reds[r * 4 + 3]);
            fr[r] = logb2[r0 + sc * RSC + r] - (mm + flog2(ss));
        }
        if (t < RSC) f[r0 + sc * RSC + t] = fr[t];

        // ---- phase 2: column partial-LSE over the 2 staged rows (LDS) ----
#pragma unroll
        for (int j = 0; j < 4; ++j) {
            const int c = j * 2048 + t * 4;
            float4 a = *(const float4*)&buf[0][c];
            float4 bb = *(const float4*)&buf[1][c];
            lse_upd2(cm[j][0], cs[j][0], a.x + fr[0], bb.x + fr[1]);
            lse_upd2(cm[j][1], cs[j][1], a.y + fr[0], bb.y + fr[1]);
            lse_upd2(cm[j][2], cs[j][2], a.z + fr[0], bb.z + fr[1]);
            lse_upd2(cm[j][3], cs[j][3], a.w + fr[0], bb.w + fr[1]);
        }
        bar_lgkm();   // barrier B: every wave done reading buf

        // ---- issue DMA for sub-chunk sc+1 (safe: all reads of buf finished) ----
        if (sc + 1 < NSUB) {
            const float* Sn = S + (size_t)(r0 + (sc + 1) * RSC + rw) * NR + qbase;
            float* ld = &buf[rw][qbase];
#pragma unroll
            for (int it = 0; it < 8; ++it)
#if __has_builtin(__builtin_amdgcn_global_load_lds)
                gl2lds16(Sn + it * 256 + loff, ld + it * 256);
#else
                gl2lds16(Sn + it * 256 + loff, ld + it * 256 + loff);
#endif
        }
    }
    // write column partials for this chunk as a single float L = m + log2(s)
#pragma unroll
    for (int j = 0; j < 4; ++j) {
        float4 L;
        L.x = cm[j][0] + flog2(cs[j][0]);
        L.y = cm[j][1] + flog2(cs[j][1]);
        L.z = cm[j][2] + flog2(cs[j][2]);
        L.w = cm[j][3] + flog2(cs[j][3]);
        *(float4*)&pm[(size_t)chunk * NR + j * 2048 + t * 4] = L;
    }
}

// ---------------- combine partials -> g (256 blocks, two-level LSE) ----------------
__global__ __launch_bounds__(256) void col_combine(const float* __restrict__ pm,
                                                   float* __restrict__ g,
                                                   float log_a2) {
    __shared__ float Lsh[8][32];
    const int cl = threadIdx.x & 31;       // column within block
    const int gp = threadIdx.x >> 5;       // chunk group (0..7), 64 chunks each
    const int col = blockIdx.x * 32 + cl;
    float m = -INFINITY, s = 0.0f;
#pragma unroll
    for (int ch = gp * 64; ch < gp * 64 + 64; ch += 4) {
        float l0 = pm[(size_t)(ch + 0) * NR + col];
        float l1 = pm[(size_t)(ch + 1) * NR + col];
        float l2 = pm[(size_t)(ch + 2) * NR + col];
        float l3 = pm[(size_t)(ch + 3) * NR + col];
        lse_upd4(m, s, l0, l1, l2, l3);
    }
    Lsh[gp][cl] = m + flog2(s);
    __syncthreads();
    if (gp == 0) {
        float mm = -INFINITY, ss = 0.0f;
        lse_upd4(mm, ss, Lsh[0][cl], Lsh[1][cl], Lsh[2][cl], Lsh[3][cl]);
        lse_upd4(mm, ss, Lsh[4][cl], Lsh[5][cl], Lsh[6][cl], Lsh[7][cl]);
        g[col] = log_a2 - (mm + flog2(ss));
    }
}

// ---------------- T = exp2(f + S + g), in place; global sum == 1 analytically ------
// note: no __restrict__ on S/out — they alias (in-place)
__global__ __launch_bounds__(256) void write_pass(const float* S,
                                                  const float* __restrict__ f,
                                                  const float* __restrict__ g,
                                                  float* out) {
    const int wv = threadIdx.x >> 6, lane = threadIdx.x & 63;
    const int row = blockIdx.x * 4 + wv;
    const float fi = f[row];
    const float4* Sr = (const float4*)(S + (size_t)row * NR);
    const float4* gr = (const float4*)g;
    float4* Or = (float4*)(out + (size_t)row * NR);
#pragma unroll 4
    for (int it = 0; it < NR / 256; ++it) {
        const int idx = it * 64 + lane;
        float4 sv = Sr[idx];
        float4 gv = gr[idx];
        float4 o;
        o.x = fexp2(fi + sv.x + gv.x);
        o.y = fexp2(fi + sv.y + gv.y);
        o.z = fexp2(fi + sv.z + gv.z);
        o.w = fexp2(fi + sv.w + gv.w);
        Or[idx] = o;
    }
}

extern "C" void kernel_launch(void* const* d_in, const int* in_sizes, int n_in,
                              void* d_out, int out_size, void* d_ws, size_t ws_size,
                              hipStream_t stream) {
    (void)in_sizes; (void)n_in; (void)out_size; (void)ws_size;
    const float* A  = (const float*)d_in[0];
    const float* Tk = (const float*)d_in[1];
    const float* Wq = (const float*)d_in[2];
    const float* bq = (const float*)d_in[3];
    const float* Wk = (const float*)d_in[4];
    const float* bk = (const float*)d_in[5];
    const float* W1 = (const float*)d_in[6];
    const float* b1 = (const float*)d_in[7];
    const float* W2 = (const float*)d_in[8];
    const float* b2 = (const float*)d_in[9];
    float* S  = (float*)d_out;           // 8192x8192 base-2 log_K lives in d_out
    float* ws = (float*)d_ws;
    float* qn     = ws; ws += NR;
    float* kn     = ws; ws += NR;
    float* logb2  = ws; ws += NR;
    float* logits = ws; ws += NR;
    float* f      = ws; ws += NR;
    float* g      = ws; ws += NR;
    float* pm     = ws; ws += (size_t)NBLK * NR;   // 16 MB
    float* q      = ws; ws += (size_t)NR * DIM;    // 8 MB
    float* k      = ws; ws += (size_t)NR * DIM;    // 8 MB
    // bf16 split arrays overlay pm (16.78 MB == 4 x NR*DIM ushorts): they are
    // dead once dist_mfma finishes, before the first iter_fused writes pm.
    ushort_t* qh = (ushort_t*)pm;
    ushort_t* ql = qh + (size_t)NR * DIM;
    ushort_t* kh = ql + (size_t)NR * DIM;
    ushort_t* kl = kh + (size_t)NR * DIM;

    const float log_a2 = -13.0f; // log2(1/8192 + 1e-20)

    init_zero<<<32, 256, 0, stream>>>(g);
    gemm_qk2<<<dim3(128, 4, 2), 256, 0, stream>>>(A, Wq, bq, q, Tk, Wk, bk, k);
    row_norm2<<<2 * NR, 64, 0, stream>>>(q, qn, k, kn);
    split_bf16_2<<<2 * (NR * DIM / 1024), 256, 0, stream>>>(q, qh, ql, k, kh, kl);
    mlp_logits<<<NR, 128, 0, stream>>>(A, W1, b1, W2, b2, logits);
    softmax_logb<<<1, 1024, 0, stream>>>(logits, logb2);
    dist_mfma<<<dim3(64, 64), 256, 0, stream>>>(qh, ql, kh, kl, qn, kn, S);
    for (int it = 0; it < 50; ++it) {
        iter_fused<<<NBLK, 512, 0, stream>>>(S, g, logb2, f, pm);
        col_combine<<<NR / 32, 256, 0, stream>>>(pm, g, log_a2);
    }
    write_pass<<<NR / 4, 256, 0, stream>>>(S, f, g, S);
}